// Round 3
// baseline (7018.067 us; speedup 1.0000x reference)
//
#include <hip/hip_runtime.h>
#include <hip/hip_bf16.h>

typedef __hip_bfloat16 bf16;

#define NN  100000   // nodes
#define EE  800000   // edges
#define FN_ 128      // node feature dim
#define FE_ 16       // edge feature dim
#define HN  200      // hidden dim
#define TT  8        // towers
#define DT_ 25       // per-tower dim
#define GG  64       // graphs
#define STEPS_ 3

#define NB  32       // nodes per GEMM block
#define KC  100      // K chunk for LDS staging
#define EB  64       // edges per msg block
#define NRB 512      // nodes per scatter block
#define MSTR 400     // bf16 row stride of m/feat overlay inside agg (800 B = one f32 agg row)

__device__ __forceinline__ float b2f(bf16 v) { return __bfloat162float(v); }
__device__ __forceinline__ float us2f(unsigned short u) { return __uint_as_float((unsigned)u << 16); }
__device__ __forceinline__ float sigmf(float x) { return 1.0f / (1.0f + __expf(-x)); }

// dtype-selected load: T = bf16 or float, p is the raw input pointer
template <typename T> struct LDR;
template <> struct LDR<bf16> {
    static __device__ __forceinline__ float get(const void* p, size_t i) {
        return __bfloat162float(((const bf16*)p)[i]);
    }
};
template <> struct LDR<float> {
    static __device__ __forceinline__ float get(const void* p, size_t i) {
        return ((const float*)p)[i];
    }
};

__device__ __forceinline__ unsigned ordkey(float x) {
    unsigned b = __float_as_uint(x);
    return b ^ (unsigned)(((int)b >> 31) | (int)0x80000000);
}
__device__ __forceinline__ float ordinv(unsigned u) {
    unsigned b = (u & 0x80000000u) ? (u ^ 0x80000000u) : ~u;
    return __uint_as_float(b);
}

// ---------------- dtype probe: bf16-read first 2048 halfwords of nf and W_in ----------------
// If the underlying data is f32, ~half the bf16 reads are f32 low-halves with random
// exponents -> many |x|>1e3 or NaN. If bf16, all |x| < ~8. Safe in both worlds.
__global__ __launch_bounds__(256) void probe_k(const void* nf, const void* Win, int* flag) {
    __shared__ int cnt;
    if (threadIdx.x == 0) cnt = 0;
    __syncthreads();
    const unsigned short* a = (const unsigned short*)nf;
    const unsigned short* b = (const unsigned short*)Win;
    int c = 0;
    for (int i = threadIdx.x; i < 2048; i += 256) {
        float x = us2f(a[i]);
        float y = us2f(b[i]);
        if (!(fabsf(x) < 1e3f)) c++;
        if (!(fabsf(y) < 1e3f)) c++;
    }
    atomicAdd(&cnt, c);
    __syncthreads();
    if (threadIdx.x == 0) flag[0] = (cnt >= 8) ? 1 : 0;
}

// ---------------- zero fill ----------------
__global__ __launch_bounds__(256) void zero_k(float4* __restrict__ p, int n4) {
    int i = blockIdx.x * 256 + threadIdx.x;
    if (i < n4) p[i] = float4{0.f, 0.f, 0.f, 0.f};
}

// ---------------- generic GEMM impl: C = act(X @ W + b), bf16 out with stride ----------------
template <typename XT, typename WT, int RELU, int OSTRIDE>
__device__ __forceinline__ void gemm_impl(
    float (*xs)[KC], const void* X, int K,
    const void* W, const void* bias, bf16* C, int Nn, int n0, int tid)
{
    float acc[NB];
#pragma unroll
    for (int n = 0; n < NB; n++) acc[n] = 0.f;

    for (int kc = 0; kc < K; kc += KC) {
        const int CS = (K - kc < KC) ? (K - kc) : KC;
        __syncthreads();
        for (int i = tid; i < NB * CS; i += 256) {
            int n = i / CS, k = i - n * CS;
            int row = n0 + n;
            xs[n][k] = (row < Nn) ? LDR<XT>::get(X, (size_t)row * K + kc + k) : 0.f;
        }
        __syncthreads();
        if (tid < HN) {
            for (int k = 0; k < CS; k += 4) {
                size_t wb = (size_t)(kc + k) * HN + tid;
                float w0 = LDR<WT>::get(W, wb);
                float w1 = LDR<WT>::get(W, wb + HN);
                float w2 = LDR<WT>::get(W, wb + 2 * HN);
                float w3 = LDR<WT>::get(W, wb + 3 * HN);
#pragma unroll
                for (int n = 0; n < NB; n++) {
                    float4 x = *(const float4*)&xs[n][k];
                    acc[n] = fmaf(x.x, w0, fmaf(x.y, w1, fmaf(x.z, w2, fmaf(x.w, w3, acc[n]))));
                }
            }
        }
    }
    if (tid < HN) {
        float b = LDR<WT>::get(bias, tid);
#pragma unroll
        for (int n = 0; n < NB; n++) {
            int row = n0 + n;
            if (row < Nn) {
                float v = acc[n] + b;
                if (RELU) v = fmaxf(v, 0.f);
                C[(size_t)row * OSTRIDE + tid] = __float2bfloat16(v);
            }
        }
    }
}

__global__ __launch_bounds__(256) void gemm_in_k(
    const int* flag, const void* X, const void* W, const void* bias, bf16* C, int Nn)
{
    __shared__ float xs[NB][KC];
    const int tid = threadIdx.x, n0 = blockIdx.x * NB;
    if (*flag) gemm_impl<float, float, 1, HN>(xs, X, FN_, W, bias, C, Nn, n0, tid);
    else       gemm_impl<bf16,  bf16,  1, HN>(xs, X, FN_, W, bias, C, Nn, n0, tid);
}

__global__ __launch_bounds__(256) void gemm_feat_k(
    const int* flag, const bf16* X, const void* W, const void* bias, bf16* C, int Nn)
{
    __shared__ float xs[NB][KC];
    const int tid = threadIdx.x, n0 = blockIdx.x * NB;
    if (*flag) gemm_impl<bf16, float, 0, MSTR>(xs, X, HN, W, bias, C, Nn, n0, tid);
    else       gemm_impl<bf16, bf16,  0, MSTR>(xs, X, HN, W, bias, C, Nn, n0, tid);
}

// ---------------- fused edge gate + gather(h bf16) + scatter(agg f32 atomics) ----------------
template <typename T>
__device__ __forceinline__ void msg_impl(
    float (*efs)[FE_], int* ss, int* ds,
    const void* ef, const int* src, const int* dst, const bf16* h,
    const void* We, const void* be, float* agg, int e0, int Ecnt, int tid)
{
    float wcol[FE_];
    float bj = 0.f;
    if (tid < HN) {
#pragma unroll
        for (int k = 0; k < FE_; k++) wcol[k] = LDR<T>::get(We, (size_t)k * HN + tid);
        bj = LDR<T>::get(be, tid);
    }
    for (int i = tid; i < EB * FE_; i += 256) {
        int e = i / FE_, k = i - e * FE_;
        int ge = e0 + e;
        efs[e][k] = (ge < Ecnt) ? LDR<T>::get(ef, (size_t)ge * FE_ + k) : 0.f;
    }
    if (tid < EB) {
        int ge = e0 + tid;
        ss[tid] = (ge < Ecnt) ? src[ge] : 0;
        ds[tid] = (ge < Ecnt) ? dst[ge] : 0;
    }
    __syncthreads();
    if (tid < HN) {
        int lim = Ecnt - e0; if (lim > EB) lim = EB;
        for (int e = 0; e < lim; e++) {
            float g = bj;
#pragma unroll
            for (int k = 0; k < FE_; k++) g = fmaf(efs[e][k], wcol[k], g);
            g = sigmf(g);
            float hv = b2f(h[(size_t)ss[e] * HN + tid]);
            atomicAdd(&agg[(size_t)ds[e] * HN + tid], g * hv);
        }
    }
}

__global__ __launch_bounds__(256) void msg_k(
    const int* flag, const void* ef, const int* src, const int* dst, const bf16* h,
    const void* We, const void* be, float* agg, int Ecnt)
{
    __shared__ float efs[EB][FE_];
    __shared__ int ss[EB], ds[EB];
    const int tid = threadIdx.x, e0 = blockIdx.x * EB;
    if (*flag) msg_impl<float>(efs, ss, ds, ef, src, dst, h, We, be, agg, e0, Ecnt, tid);
    else       msg_impl<bf16>(efs, ss, ds, ef, src, dst, h, We, be, agg, e0, Ecnt, tid);
}

// ---------------- fused tower-mix + W_mix GEMM; writes m (bf16) OVER its own agg rows ----------------
template <typename T>
__device__ __forceinline__ void mix_impl(
    float (*as)[HN], float (*ts)[HN],
    const float* agg, const void* Wt, const void* Wmix, const void* bmix,
    bf16* mb, int Nn, int n0, int tid)
{
    for (int i = tid; i < NB * HN; i += 256) {
        int n = i / HN, k = i - n * HN;
        int row = n0 + n;
        as[n][k] = (row < Nn) ? agg[(size_t)row * HN + k] : 0.f;
    }
    __syncthreads();
    for (int i = tid; i < NB * HN; i += 256) {
        int n = i / HN, te = i - n * HN;
        int t = te / DT_, e = te - t * DT_;
        float s = 0.f;
        size_t wb = (size_t)(t * DT_) * DT_ + e;
#pragma unroll
        for (int d = 0; d < DT_; d++) s = fmaf(as[n][t * DT_ + d], LDR<T>::get(Wt, wb + (size_t)d * DT_), s);
        ts[n][te] = s;
    }
    __syncthreads();
    if (tid < HN) {
        float acc[NB];
#pragma unroll
        for (int n = 0; n < NB; n++) acc[n] = 0.f;
        for (int k = 0; k < HN; k += 4) {
            size_t wb = (size_t)k * HN + tid;
            float w0 = LDR<T>::get(Wmix, wb);
            float w1 = LDR<T>::get(Wmix, wb + HN);
            float w2 = LDR<T>::get(Wmix, wb + 2 * HN);
            float w3 = LDR<T>::get(Wmix, wb + 3 * HN);
#pragma unroll
            for (int n = 0; n < NB; n++) {
                float4 x = *(const float4*)&ts[n][k];
                acc[n] = fmaf(x.x, w0, fmaf(x.y, w1, fmaf(x.z, w2, fmaf(x.w, w3, acc[n]))));
            }
        }
        float b = LDR<T>::get(bmix, tid);
#pragma unroll
        for (int n = 0; n < NB; n++) {
            int row = n0 + n;
            if (row < Nn) mb[(size_t)row * MSTR + tid] = __float2bfloat16(fmaxf(acc[n] + b, 0.f));
        }
    }
}

__global__ __launch_bounds__(256) void mix_k(
    const int* flag, const float* agg, const void* Wt, const void* Wmix, const void* bmix,
    bf16* mb, int Nn)
{
    __shared__ float as[NB][HN];
    __shared__ float ts[NB][HN];
    const int tid = threadIdx.x, n0 = blockIdx.x * NB;
    if (*flag) mix_impl<float>(as, ts, agg, Wt, Wmix, bmix, mb, Nn, n0, tid);
    else       mix_impl<bf16>(as, ts, agg, Wt, Wmix, bmix, mb, Nn, n0, tid);
}

// ---------------- fully fused GRU: h = (1-z)h + z*tanh(m@Wh + (r*h)@Uh + bh) in place ----------------
template <typename T>
__device__ __forceinline__ void gru_impl(
    float (*ms)[HN], float (*hs)[HN],
    const bf16* mb, bf16* h,
    const void* Wz, const void* Uz, const void* bz,
    const void* Wr, const void* Ur, const void* br,
    const void* Wh, const void* Uh, const void* bh,
    int Nn, int n0, int tid)
{
    // stage m and h tiles (bf16 -> f32 LDS), vectorized 4 bf16 per load
    for (int i = tid; i < NB * (HN / 4); i += 256) {
        int n = i / (HN / 4), k4 = (i - n * (HN / 4)) * 4;
        ushort4 um = *(const ushort4*)&mb[(size_t)(n0 + n) * MSTR + k4];
        ushort4 uh = *(const ushort4*)&h[(size_t)(n0 + n) * HN + k4];
        *(float4*)&ms[n][k4] = float4{us2f(um.x), us2f(um.y), us2f(um.z), us2f(um.w)};
        *(float4*)&hs[n][k4] = float4{us2f(uh.x), us2f(uh.y), us2f(uh.z), us2f(uh.w)};
    }
    __syncthreads();

    float az[NB], ar[NB], ah[NB];
#pragma unroll
    for (int n = 0; n < NB; n++) { az[n] = 0.f; ar[n] = 0.f; ah[n] = 0.f; }

    if (tid < HN) {
        for (int k = 0; k < HN; k += 4) {
            size_t wb = (size_t)k * HN + tid;
            float wz0 = LDR<T>::get(Wz, wb), wz1 = LDR<T>::get(Wz, wb + HN), wz2 = LDR<T>::get(Wz, wb + 2 * HN), wz3 = LDR<T>::get(Wz, wb + 3 * HN);
            float uz0 = LDR<T>::get(Uz, wb), uz1 = LDR<T>::get(Uz, wb + HN), uz2 = LDR<T>::get(Uz, wb + 2 * HN), uz3 = LDR<T>::get(Uz, wb + 3 * HN);
            float wr0 = LDR<T>::get(Wr, wb), wr1 = LDR<T>::get(Wr, wb + HN), wr2 = LDR<T>::get(Wr, wb + 2 * HN), wr3 = LDR<T>::get(Wr, wb + 3 * HN);
            float ur0 = LDR<T>::get(Ur, wb), ur1 = LDR<T>::get(Ur, wb + HN), ur2 = LDR<T>::get(Ur, wb + 2 * HN), ur3 = LDR<T>::get(Ur, wb + 3 * HN);
            float wh0 = LDR<T>::get(Wh, wb), wh1 = LDR<T>::get(Wh, wb + HN), wh2 = LDR<T>::get(Wh, wb + 2 * HN), wh3 = LDR<T>::get(Wh, wb + 3 * HN);
#pragma unroll
            for (int n = 0; n < NB; n++) {
                float4 xm = *(const float4*)&ms[n][k];
                float4 xh = *(const float4*)&hs[n][k];
                az[n] = fmaf(xm.x, wz0, fmaf(xm.y, wz1, fmaf(xm.z, wz2, fmaf(xm.w, wz3, az[n]))));
                az[n] = fmaf(xh.x, uz0, fmaf(xh.y, uz1, fmaf(xh.z, uz2, fmaf(xh.w, uz3, az[n]))));
                ar[n] = fmaf(xm.x, wr0, fmaf(xm.y, wr1, fmaf(xm.z, wr2, fmaf(xm.w, wr3, ar[n]))));
                ar[n] = fmaf(xh.x, ur0, fmaf(xh.y, ur1, fmaf(xh.z, ur2, fmaf(xh.w, ur3, ar[n]))));
                ah[n] = fmaf(xm.x, wh0, fmaf(xm.y, wh1, fmaf(xm.z, wh2, fmaf(xm.w, wh3, ah[n]))));
            }
        }
    }
    __syncthreads();   // all reads of hs done

    if (tid < HN) {
        float bzv = LDR<T>::get(bz, tid), brv = LDR<T>::get(br, tid);
#pragma unroll
        for (int n = 0; n < NB; n++) {
            float r = sigmf(ar[n] + brv);
            az[n] = sigmf(az[n] + bzv);      // az now holds z
            hs[n][tid] = r * hs[n][tid];     // hs now holds r*h
        }
    }
    __syncthreads();

    if (tid < HN) {
        for (int k = 0; k < HN; k += 4) {
            size_t wb = (size_t)k * HN + tid;
            float u0 = LDR<T>::get(Uh, wb), u1 = LDR<T>::get(Uh, wb + HN), u2 = LDR<T>::get(Uh, wb + 2 * HN), u3 = LDR<T>::get(Uh, wb + 3 * HN);
#pragma unroll
            for (int n = 0; n < NB; n++) {
                float4 x = *(const float4*)&hs[n][k];
                ah[n] = fmaf(x.x, u0, fmaf(x.y, u1, fmaf(x.z, u2, fmaf(x.w, u3, ah[n]))));
            }
        }
        float bhv = LDR<T>::get(bh, tid);
#pragma unroll
        for (int n = 0; n < NB; n++) {
            int row = n0 + n;
            if (row < Nn) {
                size_t idx = (size_t)row * HN + tid;
                float hv = b2f(h[idx]);
                float htl = tanhf(ah[n] + bhv);
                h[idx] = __float2bfloat16(fmaf(az[n], htl - hv, hv));
            }
        }
    }
}

__global__ __launch_bounds__(256) void gru_k(
    const int* flag, const bf16* mb, bf16* h,
    const void* Wz, const void* Uz, const void* bz,
    const void* Wr, const void* Ur, const void* br,
    const void* Wh, const void* Uh, const void* bh, int Nn)
{
    __shared__ float ms[NB][HN];
    __shared__ float hs[NB][HN];
    const int tid = threadIdx.x, n0 = blockIdx.x * NB;
    if (*flag) gru_impl<float>(ms, hs, mb, h, Wz, Uz, bz, Wr, Ur, br, Wh, Uh, bh, Nn, n0, tid);
    else       gru_impl<bf16>(ms, hs, mb, h, Wz, Uz, bz, Wr, Ur, br, Wh, Uh, bh, Nn, n0, tid);
}

// ---------------- attention score ----------------
template <typename T>
__device__ __forceinline__ void score_impl(
    const bf16* h, const void* Ws, const void* bs, float* score, int Nn, int node, int lane)
{
    if (node >= Nn) return;
    float a = 0.f;
    for (int k = lane; k < HN; k += 64) a = fmaf(b2f(h[(size_t)node * HN + k]), LDR<T>::get(Ws, k), a);
    for (int off = 32; off; off >>= 1) a += __shfl_down(a, off, 64);
    if (lane == 0) score[node] = a + LDR<T>::get(bs, 0);
}

__global__ __launch_bounds__(256) void score_k(
    const int* flag, const bf16* h, const void* Ws, const void* bs, float* score, int Nn)
{
    int node = blockIdx.x * 4 + (threadIdx.x >> 6);
    int lane = threadIdx.x & 63;
    if (*flag) score_impl<float>(h, Ws, bs, score, Nn, node, lane);
    else       score_impl<bf16>(h, Ws, bs, score, Nn, node, lane);
}

// ---------------- segment max ----------------
__global__ __launch_bounds__(256) void gmax_k(
    const float* __restrict__ score, const int* __restrict__ bv,
    unsigned* __restrict__ gmax_u, int Nn)
{
    __shared__ unsigned lm[GG];
    const int tid = threadIdx.x;
    for (int i = tid; i < GG; i += 256) lm[i] = 0u;
    __syncthreads();
    int n = blockIdx.x * 256 + tid;
    if (n < Nn) atomicMax(&lm[bv[n]], ordkey(score[n]));
    __syncthreads();
    for (int i = tid; i < GG; i += 256)
        if (lm[i]) atomicMax(&gmax_u[i], lm[i]);
}

// ---------------- exp + segment sum ----------------
__global__ __launch_bounds__(256) void exsum_k(
    const float* __restrict__ score, const int* __restrict__ bv,
    const unsigned* __restrict__ gmax_u, float* __restrict__ ex,
    float* __restrict__ gsum, int Nn)
{
    __shared__ float ls[GG];
    const int tid = threadIdx.x;
    for (int i = tid; i < GG; i += 256) ls[i] = 0.f;
    __syncthreads();
    int n = blockIdx.x * 256 + tid;
    if (n < Nn) {
        int g = bv[n];
        float e = __expf(score[n] - ordinv(gmax_u[g]));
        ex[n] = e;
        atomicAdd(&ls[g], e);
    }
    __syncthreads();
    for (int i = tid; i < GG; i += 256)
        if (ls[i] != 0.f) atomicAdd(&gsum[i], ls[i]);
}

// ---------------- weighted readout scatter ----------------
__global__ __launch_bounds__(256) void scatter_k(
    const bf16* __restrict__ feat, const float* __restrict__ ex,
    const float* __restrict__ gsum, const int* __restrict__ bv,
    float* __restrict__ gout, int Nn)
{
    const int tid = threadIdx.x;
    if (tid >= HN) return;
    int n0 = blockIdx.x * NRB;
    int lim = Nn - n0; if (lim > NRB) lim = NRB;
    float acc = 0.f;
    int cur = -1;
    float inv = 0.f;
    for (int i = 0; i < lim; i++) {
        int n = n0 + i;
        int g = bv[n];
        if (g != cur) {
            if (cur >= 0) atomicAdd(&gout[cur * HN + tid], acc);
            acc = 0.f;
            cur = g;
            inv = 1.0f / gsum[g];
        }
        acc = fmaf(ex[n] * inv, b2f(feat[(size_t)n * MSTR + tid]), acc);
    }
    if (cur >= 0) atomicAdd(&gout[cur * HN + tid], acc);
}

// ---------------- readout MLP ----------------
template <typename T, int OUTF32>
__device__ __forceinline__ void final_impl(
    float* r1s, const float* gout,
    const void* Wr1, const void* br1, const void* Wout, const void* bout,
    void* out, int g, int tid)
{
    if (tid < HN) {
        float v = LDR<T>::get(br1, tid);
        for (int k = 0; k < HN; k++) v = fmaf(gout[g * HN + k], LDR<T>::get(Wr1, (size_t)k * HN + tid), v);
        r1s[tid] = (v == v) ? fmaxf(v, 0.f) : v;   // NaN-PROPAGATING relu (diagnostic)
    }
    __syncthreads();
    if (tid < 64) {
        float a = 0.f;
        for (int k = tid; k < HN; k += 64) a = fmaf(r1s[k], LDR<T>::get(Wout, k), a);
        for (int off = 32; off; off >>= 1) a += __shfl_down(a, off, 64);
        if (tid == 0) {
            float res = a + LDR<T>::get(bout, 0);
            if (OUTF32) ((float*)out)[g] = res;
            else        ((bf16*)out)[g] = __float2bfloat16(res);
        }
    }
}

__global__ __launch_bounds__(256) void final_k(
    const int* flag, const float* gout,
    const void* Wr1, const void* br1, const void* Wout, const void* bout, void* out)
{
    __shared__ float r1s[HN];
    const int g = blockIdx.x, tid = threadIdx.x;
    if (*flag) final_impl<float, 1>(r1s, gout, Wr1, br1, Wout, bout, out, g, tid);
    else       final_impl<bf16,  0>(r1s, gout, Wr1, br1, Wout, bout, out, g, tid);
}

extern "C" void kernel_launch(void* const* d_in, const int* in_sizes, int n_in,
                              void* d_out, int out_size, void* d_ws, size_t ws_size,
                              hipStream_t stream)
{
    const void* nf      = d_in[0];
    const void* ef      = d_in[1];
    const int*  ei      = (const int*)d_in[2];
    const int*  bv      = (const int*)d_in[3];
    const void* W_in    = d_in[4];
    const void* b_in    = d_in[5];
    const void* W_edge  = d_in[6];
    const void* b_edge  = d_in[7];
    const void* W_tower = d_in[8];
    const void* W_mix   = d_in[9];
    const void* b_mix   = d_in[10];
    const void* Wz      = d_in[11];
    const void* Uz      = d_in[12];
    const void* bz      = d_in[13];
    const void* Wr      = d_in[14];
    const void* Ur      = d_in[15];
    const void* br      = d_in[16];
    const void* Wh      = d_in[17];
    const void* Uh      = d_in[18];
    const void* bh      = d_in[19];
    const void* W_score = d_in[20];
    const void* b_score = d_in[21];
    const void* W_feat  = d_in[22];
    const void* b_feat  = d_in[23];
    const void* W_r1    = d_in[24];
    const void* b_r1    = d_in[25];
    const void* W_out   = d_in[26];
    const void* b_out   = d_in[27];

    const int* src = ei;
    const int* dst = ei + EE;

    // workspace layout (~121 MB, proven fault-free in round 2):
    //   h    : N*H bf16              40,000,000 B
    //   agg  : N*H f32               80,000,000 B  (m/feat bf16 overlay, row stride MSTR)
    //   score/ex : N f32 each           800,000 B
    //   gmax_u/gsum/gout/flag            51,716 B
    const size_t NH = (size_t)NN * HN;
    bf16* h      = (bf16*)d_ws;
    float* agg   = (float*)(h + NH);
    bf16* mb     = (bf16*)agg;              // overlay
    float* score = agg + NH;
    float* ex    = score + NN;
    unsigned* gmax_u = (unsigned*)(ex + NN);
    float* gsum  = (float*)(gmax_u + GG);
    float* gout  = gsum + GG;
    int*   flag  = (int*)(gout + (size_t)GG * HN);

    const dim3 blk(256);
    const int zgrid_big = (int)((NH / 4 + 255) / 256);
    const int zsmall_n4 = (GG + GG + GG * HN) / 4;
    const int zgrid_small = (zsmall_n4 + 255) / 256;

    probe_k<<<dim3(1), blk, 0, stream>>>(nf, W_in, flag);

    // h = relu(nf @ W_in + b_in)  -> bf16
    gemm_in_k<<<dim3(NN / NB), blk, 0, stream>>>(flag, nf, W_in, b_in, h, NN);

    for (int s = 0; s < STEPS_; s++) {
        zero_k<<<dim3(zgrid_big), blk, 0, stream>>>((float4*)agg, (int)(NH / 4));
        msg_k<<<dim3(EE / EB), blk, 0, stream>>>(flag, ef, src, dst, h, W_edge, b_edge, agg, EE);
        mix_k<<<dim3(NN / NB), blk, 0, stream>>>(flag, agg, W_tower, W_mix, b_mix, mb, NN);
        gru_k<<<dim3(NN / NB), blk, 0, stream>>>(flag, mb, h, Wz, Uz, bz, Wr, Ur, br, Wh, Uh, bh, NN);
    }

    // attention readout
    score_k<<<dim3((NN + 3) / 4), blk, 0, stream>>>(flag, h, W_score, b_score, score, NN);
    zero_k<<<dim3(zgrid_small), blk, 0, stream>>>((float4*)gmax_u, zsmall_n4);
    gmax_k<<<dim3((NN + 255) / 256), blk, 0, stream>>>(score, bv, gmax_u, NN);
    exsum_k<<<dim3((NN + 255) / 256), blk, 0, stream>>>(score, bv, gmax_u, ex, gsum, NN);
    // feat = h @ W_feat + b_feat  -> bf16 overlay (agg is dead now)
    gemm_feat_k<<<dim3(NN / NB), blk, 0, stream>>>(flag, h, W_feat, b_feat, mb, NN);
    scatter_k<<<dim3((NN + NRB - 1) / NRB), blk, 0, stream>>>(mb, ex, gsum, bv, gout, NN);
    final_k<<<dim3(GG), blk, 0, stream>>>(flag, gout, W_r1, b_r1, W_out, b_out, d_out);
}

// Round 4
// 4955.771 us; speedup vs baseline: 1.4161x; 1.4161x over previous
//
#include <hip/hip_runtime.h>
#include <hip/hip_bf16.h>

typedef __hip_bfloat16 bf16;

#define NN  100000   // nodes
#define EE  800000   // edges
#define FN_ 128      // node feature dim
#define FE_ 16       // edge feature dim
#define HN  200      // hidden dim
#define TT  8        // towers
#define DT_ 25       // per-tower dim
#define GG  64       // graphs
#define STEPS_ 3

#define NB  32       // nodes per GEMM block
#define KC  100      // K chunk for LDS staging
#define EB  64       // edges per msg block
#define NRB 512      // nodes per scatter block
#define MSTR 400     // bf16 row stride of m/feat overlay inside agg

// MFMA GRU geometry
#define MB   32      // nodes per gru block (2 row-tiles of 16)
#define XSTR 456     // LDS X row stride in shorts (448 padded K + 8)
#define CTN  13      // col tiles (13*16 = 208 >= 200)
#define KTN  14      // k tiles   (14*32 = 448 = 224(m) + 224(h))
#define WBSZ (3 * KTN * CTN * 512)   // packed weight shorts

typedef __attribute__((ext_vector_type(8))) short short8v;
typedef __attribute__((ext_vector_type(4))) float f32x4;
#define MFMA16(a, b, c) __builtin_amdgcn_mfma_f32_16x16x32_bf16(a, b, c, 0, 0, 0)

__device__ __forceinline__ float b2f(bf16 v) { return __bfloat162float(v); }
__device__ __forceinline__ float us2f(unsigned short u) { return __uint_as_float((unsigned)u << 16); }
__device__ __forceinline__ float sigmf(float x) { return 1.0f / (1.0f + __expf(-x)); }

template <typename T> struct LDR;
template <> struct LDR<bf16> {
    static __device__ __forceinline__ float get(const void* p, size_t i) {
        return __bfloat162float(((const bf16*)p)[i]);
    }
};
template <> struct LDR<float> {
    static __device__ __forceinline__ float get(const void* p, size_t i) {
        return ((const float*)p)[i];
    }
};

__device__ __forceinline__ unsigned ordkey(float x) {
    unsigned b = __float_as_uint(x);
    return b ^ (unsigned)(((int)b >> 31) | (int)0x80000000);
}
__device__ __forceinline__ float ordinv(unsigned u) {
    unsigned b = (u & 0x80000000u) ? (u ^ 0x80000000u) : ~u;
    return __uint_as_float(b);
}

// ---------------- dtype probe ----------------
__global__ __launch_bounds__(256) void probe_k(const void* nf, const void* Win, int* flag) {
    __shared__ int cnt;
    if (threadIdx.x == 0) cnt = 0;
    __syncthreads();
    const unsigned short* a = (const unsigned short*)nf;
    const unsigned short* b = (const unsigned short*)Win;
    int c = 0;
    for (int i = threadIdx.x; i < 2048; i += 256) {
        float x = us2f(a[i]);
        float y = us2f(b[i]);
        if (!(fabsf(x) < 1e3f)) c++;
        if (!(fabsf(y) < 1e3f)) c++;
    }
    atomicAdd(&cnt, c);
    __syncthreads();
    if (threadIdx.x == 0) flag[0] = (cnt >= 8) ? 1 : 0;
}

// ---------------- zero fill ----------------
__global__ __launch_bounds__(256) void zero_k(float4* __restrict__ p, int n4) {
    int i = blockIdx.x * 256 + threadIdx.x;
    if (i < n4) p[i] = float4{0.f, 0.f, 0.f, 0.f};
}

// ---------------- GRU weight pack: f32/bf16 -> bf16 B-fragment layout ----------------
// WB[((g*14+kt)*13+ct)*512 + lane*8 + j] = W_g[kt*32 + (lane>>4)*8 + j][ct*16 + (lane&15)]
// g=0: [Wz; Uz], g=1: [Wr; Ur], g=2: [Wh; Uh]; k 0..223 = W rows (valid<200), 224..447 = U rows.
__global__ __launch_bounds__(256) void pack_k(
    const int* flag,
    const void* Wz, const void* Uz, const void* bz,
    const void* Wr, const void* Ur, const void* br,
    const void* Wh, const void* Uh, const void* bh,
    short* __restrict__ WB, float* __restrict__ bpack)
{
    int i = blockIdx.x * 256 + threadIdx.x;
    int f = *flag;
    if (i < WBSZ) {
        int j8 = i & 7;
        int e = i >> 3;
        int lane = e & 63; e >>= 6;
        int ct = e % 13; e /= 13;
        int kt = e % 14;
        int g = e / 14;
        int kl = kt * 32 + (lane >> 4) * 8 + j8;
        int col = ct * 16 + (lane & 15);
        int ksrc = (kl < 224) ? kl : kl - 224;
        const void* W = (kl < 224) ? (g == 0 ? Wz : g == 1 ? Wr : Wh)
                                   : (g == 0 ? Uz : g == 1 ? Ur : Uh);
        float v = 0.f;
        if (ksrc < HN && col < HN)
            v = f ? LDR<float>::get(W, (size_t)ksrc * HN + col)
                  : LDR<bf16>::get(W, (size_t)ksrc * HN + col);
        bf16 t = __float2bfloat16(v);
        WB[i] = *(short*)&t;
    } else {
        int t = i - WBSZ;
        if (t < 3 * 208) {
            int g = t / 208, col = t % 208;
            const void* B = g == 0 ? bz : g == 1 ? br : bh;
            bpack[t] = (col < HN) ? (f ? LDR<float>::get(B, col) : LDR<bf16>::get(B, col)) : 0.f;
        }
    }
}

// ---------------- MFMA GRU: 3 waves (z | r | h~), in-place h update ----------------
__global__ __launch_bounds__(192) void gru_mfma_k(
    const bf16* __restrict__ mb, bf16* __restrict__ h,
    const short* __restrict__ WB, const float* __restrict__ bpack, int Nn)
{
    __shared__ unsigned short Xs[MB][XSTR];   // [m(0..199) pad..223 | h(224..423) pad..455]
    __shared__ float zbuf[MB][CTN * 16];
    const int tid = threadIdx.x;
    const int g = tid >> 6, lane = tid & 63;
    const int qd = lane >> 4, c0 = lane & 15;
    const int n0 = blockIdx.x * MB;

    // stage X = [m | h] bf16 with zero pads
    for (int i = tid; i < MB * (XSTR / 4); i += 192) {
        int row = i / (XSTR / 4);
        int c4 = (i - row * (XSTR / 4)) * 4;
        ushort4 v = ushort4{0, 0, 0, 0};
        if (c4 < HN)
            v = *(const ushort4*)&mb[(size_t)(n0 + row) * MSTR + c4];
        else if (c4 >= 224 && c4 < 224 + HN)
            v = *(const ushort4*)&h[(size_t)(n0 + row) * HN + (c4 - 224)];
        *(ushort4*)&Xs[row][c4] = v;
    }
    __syncthreads();

    f32x4 acc[2][CTN];
#pragma unroll
    for (int mt = 0; mt < 2; mt++)
#pragma unroll
        for (int ct = 0; ct < CTN; ct++)
            acc[mt][ct] = f32x4{0.f, 0.f, 0.f, 0.f};

    // phase 1: z,r over full K=448 ; h~ over m-part (kt 0..6)
    const int ktEnd = (g == 2) ? 7 : KTN;
    for (int kt = 0; kt < ktEnd; kt++) {
        short8v a0 = *(const short8v*)&Xs[c0][kt * 32 + qd * 8];
        short8v a1 = *(const short8v*)&Xs[16 + c0][kt * 32 + qd * 8];
        const short* wp = WB + (size_t)(g * KTN + kt) * CTN * 512 + lane * 8;
#pragma unroll
        for (int ct = 0; ct < CTN; ct++) {
            short8v b = *(const short8v*)(wp + (size_t)ct * 512);
            acc[0][ct] = MFMA16(a0, b, acc[0][ct]);
            acc[1][ct] = MFMA16(a1, b, acc[1][ct]);
        }
    }
    __syncthreads();   // everyone done with phase-1 reads of Xs

    if (g == 0) {      // z -> zbuf (f32)
#pragma unroll
        for (int mt = 0; mt < 2; mt++)
#pragma unroll
            for (int ct = 0; ct < CTN; ct++)
#pragma unroll
                for (int r = 0; r < 4; r++) {
                    int row = mt * 16 + qd * 4 + r;
                    int col = ct * 16 + c0;
                    zbuf[row][col] = sigmf(acc[mt][ct][r] + bpack[col]);
                }
    } else if (g == 1) {  // r -> overwrite Xs h-region with bf16(r*h)
#pragma unroll
        for (int mt = 0; mt < 2; mt++)
#pragma unroll
            for (int ct = 0; ct < CTN; ct++)
#pragma unroll
                for (int r = 0; r < 4; r++) {
                    int row = mt * 16 + qd * 4 + r;
                    int col = ct * 16 + c0;
                    float rr = sigmf(acc[mt][ct][r] + bpack[208 + col]);
                    float hv = us2f(Xs[row][224 + col]);
                    bf16 t = __float2bfloat16(rr * hv);
                    Xs[row][224 + col] = *(unsigned short*)&t;
                }
    }
    __syncthreads();   // r*h and zbuf visible

    if (g == 2) {
        // phase 2: (r*h) @ Uh  (kt 7..13 hit the Uh rows of the g=2 pack)
        for (int kt = 7; kt < KTN; kt++) {
            short8v a0 = *(const short8v*)&Xs[c0][kt * 32 + qd * 8];
            short8v a1 = *(const short8v*)&Xs[16 + c0][kt * 32 + qd * 8];
            const short* wp = WB + (size_t)(2 * KTN + kt) * CTN * 512 + lane * 8;
#pragma unroll
            for (int ct = 0; ct < CTN; ct++) {
                short8v b = *(const short8v*)(wp + (size_t)ct * 512);
                acc[0][ct] = MFMA16(a0, b, acc[0][ct]);
                acc[1][ct] = MFMA16(a1, b, acc[1][ct]);
            }
        }
        // epilogue: h = h + z*(tanh(ah+bh) - h)
#pragma unroll
        for (int mt = 0; mt < 2; mt++)
#pragma unroll
            for (int ct = 0; ct < CTN; ct++)
#pragma unroll
                for (int r = 0; r < 4; r++) {
                    int row = mt * 16 + qd * 4 + r;
                    int col = ct * 16 + c0;
                    if (col < HN) {
                        float ah = acc[mt][ct][r] + bpack[416 + col];
                        ah = fminf(fmaxf(ah, -15.f), 15.f);
                        float e = __expf(2.f * ah);
                        float htl = (e - 1.f) / (e + 1.f);
                        size_t idx = (size_t)(n0 + row) * HN + col;
                        float hv = b2f(h[idx]);
                        h[idx] = __float2bfloat16(fmaf(zbuf[row][col], htl - hv, hv));
                    }
                }
    }
}

// ---------------- generic GEMM impl (VALU): C = act(X @ W + b), bf16 out ----------------
template <typename XT, typename WT, int RELU, int OSTRIDE>
__device__ __forceinline__ void gemm_impl(
    float (*xs)[KC], const void* X, int K,
    const void* W, const void* bias, bf16* C, int Nn, int n0, int tid)
{
    float acc[NB];
#pragma unroll
    for (int n = 0; n < NB; n++) acc[n] = 0.f;

    for (int kc = 0; kc < K; kc += KC) {
        const int CS = (K - kc < KC) ? (K - kc) : KC;
        __syncthreads();
        for (int i = tid; i < NB * CS; i += 256) {
            int n = i / CS, k = i - n * CS;
            int row = n0 + n;
            xs[n][k] = (row < Nn) ? LDR<XT>::get(X, (size_t)row * K + kc + k) : 0.f;
        }
        __syncthreads();
        if (tid < HN) {
            for (int k = 0; k < CS; k += 4) {
                size_t wb = (size_t)(kc + k) * HN + tid;
                float w0 = LDR<WT>::get(W, wb);
                float w1 = LDR<WT>::get(W, wb + HN);
                float w2 = LDR<WT>::get(W, wb + 2 * HN);
                float w3 = LDR<WT>::get(W, wb + 3 * HN);
#pragma unroll
                for (int n = 0; n < NB; n++) {
                    float4 x = *(const float4*)&xs[n][k];
                    acc[n] = fmaf(x.x, w0, fmaf(x.y, w1, fmaf(x.z, w2, fmaf(x.w, w3, acc[n]))));
                }
            }
        }
    }
    if (tid < HN) {
        float b = LDR<WT>::get(bias, tid);
#pragma unroll
        for (int n = 0; n < NB; n++) {
            int row = n0 + n;
            if (row < Nn) {
                float v = acc[n] + b;
                if (RELU) v = fmaxf(v, 0.f);
                C[(size_t)row * OSTRIDE + tid] = __float2bfloat16(v);
            }
        }
    }
}

__global__ __launch_bounds__(256) void gemm_in_k(
    const int* flag, const void* X, const void* W, const void* bias, bf16* C, int Nn)
{
    __shared__ float xs[NB][KC];
    const int tid = threadIdx.x, n0 = blockIdx.x * NB;
    if (*flag) gemm_impl<float, float, 1, HN>(xs, X, FN_, W, bias, C, Nn, n0, tid);
    else       gemm_impl<bf16,  bf16,  1, HN>(xs, X, FN_, W, bias, C, Nn, n0, tid);
}

__global__ __launch_bounds__(256) void gemm_feat_k(
    const int* flag, const bf16* X, const void* W, const void* bias, bf16* C, int Nn)
{
    __shared__ float xs[NB][KC];
    const int tid = threadIdx.x, n0 = blockIdx.x * NB;
    if (*flag) gemm_impl<bf16, float, 0, MSTR>(xs, X, HN, W, bias, C, Nn, n0, tid);
    else       gemm_impl<bf16, bf16,  0, MSTR>(xs, X, HN, W, bias, C, Nn, n0, tid);
}

// ---------------- fused edge gate + gather + scatter ----------------
template <typename T>
__device__ __forceinline__ void msg_impl(
    float (*efs)[FE_], int* ss, int* ds,
    const void* ef, const int* src, const int* dst, const bf16* h,
    const void* We, const void* be, float* agg, int e0, int Ecnt, int tid)
{
    float wcol[FE_];
    float bj = 0.f;
    if (tid < HN) {
#pragma unroll
        for (int k = 0; k < FE_; k++) wcol[k] = LDR<T>::get(We, (size_t)k * HN + tid);
        bj = LDR<T>::get(be, tid);
    }
    for (int i = tid; i < EB * FE_; i += 256) {
        int e = i / FE_, k = i - e * FE_;
        int ge = e0 + e;
        efs[e][k] = (ge < Ecnt) ? LDR<T>::get(ef, (size_t)ge * FE_ + k) : 0.f;
    }
    if (tid < EB) {
        int ge = e0 + tid;
        ss[tid] = (ge < Ecnt) ? src[ge] : 0;
        ds[tid] = (ge < Ecnt) ? dst[ge] : 0;
    }
    __syncthreads();
    if (tid < HN) {
        int lim = Ecnt - e0; if (lim > EB) lim = EB;
        for (int e = 0; e < lim; e++) {
            float g = bj;
#pragma unroll
            for (int k = 0; k < FE_; k++) g = fmaf(efs[e][k], wcol[k], g);
            g = sigmf(g);
            float hv = b2f(h[(size_t)ss[e] * HN + tid]);
            atomicAdd(&agg[(size_t)ds[e] * HN + tid], g * hv);
        }
    }
}

__global__ __launch_bounds__(256) void msg_k(
    const int* flag, const void* ef, const int* src, const int* dst, const bf16* h,
    const void* We, const void* be, float* agg, int Ecnt)
{
    __shared__ float efs[EB][FE_];
    __shared__ int ss[EB], ds[EB];
    const int tid = threadIdx.x, e0 = blockIdx.x * EB;
    if (*flag) msg_impl<float>(efs, ss, ds, ef, src, dst, h, We, be, agg, e0, Ecnt, tid);
    else       msg_impl<bf16>(efs, ss, ds, ef, src, dst, h, We, be, agg, e0, Ecnt, tid);
}

// ---------------- fused tower-mix + W_mix GEMM ----------------
template <typename T>
__device__ __forceinline__ void mix_impl(
    float (*as)[HN], float (*ts)[HN],
    const float* agg, const void* Wt, const void* Wmix, const void* bmix,
    bf16* mb, int Nn, int n0, int tid)
{
    for (int i = tid; i < NB * HN; i += 256) {
        int n = i / HN, k = i - n * HN;
        int row = n0 + n;
        as[n][k] = (row < Nn) ? agg[(size_t)row * HN + k] : 0.f;
    }
    __syncthreads();
    for (int i = tid; i < NB * HN; i += 256) {
        int n = i / HN, te = i - n * HN;
        int t = te / DT_, e = te - t * DT_;
        float s = 0.f;
        size_t wb = (size_t)(t * DT_) * DT_ + e;
#pragma unroll
        for (int d = 0; d < DT_; d++) s = fmaf(as[n][t * DT_ + d], LDR<T>::get(Wt, wb + (size_t)d * DT_), s);
        ts[n][te] = s;
    }
    __syncthreads();
    if (tid < HN) {
        float acc[NB];
#pragma unroll
        for (int n = 0; n < NB; n++) acc[n] = 0.f;
        for (int k = 0; k < HN; k += 4) {
            size_t wb = (size_t)k * HN + tid;
            float w0 = LDR<T>::get(Wmix, wb);
            float w1 = LDR<T>::get(Wmix, wb + HN);
            float w2 = LDR<T>::get(Wmix, wb + 2 * HN);
            float w3 = LDR<T>::get(Wmix, wb + 3 * HN);
#pragma unroll
            for (int n = 0; n < NB; n++) {
                float4 x = *(const float4*)&ts[n][k];
                acc[n] = fmaf(x.x, w0, fmaf(x.y, w1, fmaf(x.z, w2, fmaf(x.w, w3, acc[n]))));
            }
        }
        float b = LDR<T>::get(bmix, tid);
#pragma unroll
        for (int n = 0; n < NB; n++) {
            int row = n0 + n;
            if (row < Nn) mb[(size_t)row * MSTR + tid] = __float2bfloat16(fmaxf(acc[n] + b, 0.f));
        }
    }
}

__global__ __launch_bounds__(256) void mix_k(
    const int* flag, const float* agg, const void* Wt, const void* Wmix, const void* bmix,
    bf16* mb, int Nn)
{
    __shared__ float as[NB][HN];
    __shared__ float ts[NB][HN];
    const int tid = threadIdx.x, n0 = blockIdx.x * NB;
    if (*flag) mix_impl<float>(as, ts, agg, Wt, Wmix, bmix, mb, Nn, n0, tid);
    else       mix_impl<bf16>(as, ts, agg, Wt, Wmix, bmix, mb, Nn, n0, tid);
}

// ---------------- attention score ----------------
template <typename T>
__device__ __forceinline__ void score_impl(
    const bf16* h, const void* Ws, const void* bs, float* score, int Nn, int node, int lane)
{
    if (node >= Nn) return;
    float a = 0.f;
    for (int k = lane; k < HN; k += 64) a = fmaf(b2f(h[(size_t)node * HN + k]), LDR<T>::get(Ws, k), a);
    for (int off = 32; off; off >>= 1) a += __shfl_down(a, off, 64);
    if (lane == 0) score[node] = a + LDR<T>::get(bs, 0);
}

__global__ __launch_bounds__(256) void score_k(
    const int* flag, const bf16* h, const void* Ws, const void* bs, float* score, int Nn)
{
    int node = blockIdx.x * 4 + (threadIdx.x >> 6);
    int lane = threadIdx.x & 63;
    if (*flag) score_impl<float>(h, Ws, bs, score, Nn, node, lane);
    else       score_impl<bf16>(h, Ws, bs, score, Nn, node, lane);
}

// ---------------- segment max ----------------
__global__ __launch_bounds__(256) void gmax_k(
    const float* __restrict__ score, const int* __restrict__ bv,
    unsigned* __restrict__ gmax_u, int Nn)
{
    __shared__ unsigned lm[GG];
    const int tid = threadIdx.x;
    for (int i = tid; i < GG; i += 256) lm[i] = 0u;
    __syncthreads();
    int n = blockIdx.x * 256 + tid;
    if (n < Nn) atomicMax(&lm[bv[n]], ordkey(score[n]));
    __syncthreads();
    for (int i = tid; i < GG; i += 256)
        if (lm[i]) atomicMax(&gmax_u[i], lm[i]);
}

// ---------------- exp + segment sum ----------------
__global__ __launch_bounds__(256) void exsum_k(
    const float* __restrict__ score, const int* __restrict__ bv,
    const unsigned* __restrict__ gmax_u, float* __restrict__ ex,
    float* __restrict__ gsum, int Nn)
{
    __shared__ float ls[GG];
    const int tid = threadIdx.x;
    for (int i = tid; i < GG; i += 256) ls[i] = 0.f;
    __syncthreads();
    int n = blockIdx.x * 256 + tid;
    if (n < Nn) {
        int g = bv[n];
        float e = __expf(score[n] - ordinv(gmax_u[g]));
        ex[n] = e;
        atomicAdd(&ls[g], e);
    }
    __syncthreads();
    for (int i = tid; i < GG; i += 256)
        if (ls[i] != 0.f) atomicAdd(&gsum[i], ls[i]);
}

// ---------------- weighted readout scatter ----------------
__global__ __launch_bounds__(256) void scatter_k(
    const bf16* __restrict__ feat, const float* __restrict__ ex,
    const float* __restrict__ gsum, const int* __restrict__ bv,
    float* __restrict__ gout, int Nn)
{
    const int tid = threadIdx.x;
    if (tid >= HN) return;
    int n0 = blockIdx.x * NRB;
    int lim = Nn - n0; if (lim > NRB) lim = NRB;
    float acc = 0.f;
    int cur = -1;
    float inv = 0.f;
    for (int i = 0; i < lim; i++) {
        int n = n0 + i;
        int g = bv[n];
        if (g != cur) {
            if (cur >= 0) atomicAdd(&gout[cur * HN + tid], acc);
            acc = 0.f;
            cur = g;
            inv = 1.0f / gsum[g];
        }
        acc = fmaf(ex[n] * inv, b2f(feat[(size_t)n * MSTR + tid]), acc);
    }
    if (cur >= 0) atomicAdd(&gout[cur * HN + tid], acc);
}

// ---------------- readout MLP ----------------
template <typename T, int OUTF32>
__device__ __forceinline__ void final_impl(
    float* r1s, const float* gout,
    const void* Wr1, const void* br1, const void* Wout, const void* bout,
    void* out, int g, int tid)
{
    if (tid < HN) {
        float v = LDR<T>::get(br1, tid);
        for (int k = 0; k < HN; k++) v = fmaf(gout[g * HN + k], LDR<T>::get(Wr1, (size_t)k * HN + tid), v);
        r1s[tid] = (v == v) ? fmaxf(v, 0.f) : v;
    }
    __syncthreads();
    if (tid < 64) {
        float a = 0.f;
        for (int k = tid; k < HN; k += 64) a = fmaf(r1s[k], LDR<T>::get(Wout, k), a);
        for (int off = 32; off; off >>= 1) a += __shfl_down(a, off, 64);
        if (tid == 0) {
            float res = a + LDR<T>::get(bout, 0);
            if (OUTF32) ((float*)out)[g] = res;
            else        ((bf16*)out)[g] = __float2bfloat16(res);
        }
    }
}

__global__ __launch_bounds__(256) void final_k(
    const int* flag, const float* gout,
    const void* Wr1, const void* br1, const void* Wout, const void* bout, void* out)
{
    __shared__ float r1s[HN];
    const int g = blockIdx.x, tid = threadIdx.x;
    if (*flag) final_impl<float, 1>(r1s, gout, Wr1, br1, Wout, bout, out, g, tid);
    else       final_impl<bf16,  0>(r1s, gout, Wr1, br1, Wout, bout, out, g, tid);
}

extern "C" void kernel_launch(void* const* d_in, const int* in_sizes, int n_in,
                              void* d_out, int out_size, void* d_ws, size_t ws_size,
                              hipStream_t stream)
{
    const void* nf      = d_in[0];
    const void* ef      = d_in[1];
    const int*  ei      = (const int*)d_in[2];
    const int*  bv      = (const int*)d_in[3];
    const void* W_in    = d_in[4];
    const void* b_in    = d_in[5];
    const void* W_edge  = d_in[6];
    const void* b_edge  = d_in[7];
    const void* W_tower = d_in[8];
    const void* W_mix   = d_in[9];
    const void* b_mix   = d_in[10];
    const void* Wz      = d_in[11];
    const void* Uz      = d_in[12];
    const void* bz      = d_in[13];
    const void* Wr      = d_in[14];
    const void* Ur      = d_in[15];
    const void* br      = d_in[16];
    const void* Wh      = d_in[17];
    const void* Uh      = d_in[18];
    const void* bh      = d_in[19];
    const void* W_score = d_in[20];
    const void* b_score = d_in[21];
    const void* W_feat  = d_in[22];
    const void* b_feat  = d_in[23];
    const void* W_r1    = d_in[24];
    const void* b_r1    = d_in[25];
    const void* W_out   = d_in[26];
    const void* b_out   = d_in[27];

    const int* src = ei;
    const int* dst = ei + EE;

    // workspace layout (~122.2 MB):
    const size_t NH = (size_t)NN * HN;
    bf16* h      = (bf16*)d_ws;                     // 40 MB
    float* agg   = (float*)(h + NH);                // 80 MB (m/feat bf16 overlay)
    bf16* mb     = (bf16*)agg;
    float* score = agg + NH;
    float* ex    = score + NN;
    unsigned* gmax_u = (unsigned*)(ex + NN);
    float* gsum  = (float*)(gmax_u + GG);
    float* gout  = gsum + GG;
    short* WB    = (short*)(((uintptr_t)(gout + (size_t)GG * HN) + 15) & ~(uintptr_t)15);
    float* bpack = (float*)(WB + WBSZ);
    int*   flag  = (int*)(bpack + 3 * 208);

    const dim3 blk(256);
    const int zgrid_big = (int)((NH / 4 + 255) / 256);
    const int zsmall_n4 = (GG + GG + GG * HN) / 4;
    const int zgrid_small = (zsmall_n4 + 255) / 256;
    const int pack_grid = (WBSZ + 3 * 208 + 255) / 256;

    probe_k<<<dim3(1), blk, 0, stream>>>(nf, W_in, flag);
    pack_k<<<dim3(pack_grid), blk, 0, stream>>>(flag, Wz, Uz, bz, Wr, Ur, br, Wh, Uh, bh, WB, bpack);

    // h = relu(nf @ W_in + b_in)  -> bf16
    gemm_in_k<<<dim3(NN / NB), blk, 0, stream>>>(flag, nf, W_in, b_in, h, NN);

    for (int s = 0; s < STEPS_; s++) {
        zero_k<<<dim3(zgrid_big), blk, 0, stream>>>((float4*)agg, (int)(NH / 4));
        msg_k<<<dim3(EE / EB), blk, 0, stream>>>(flag, ef, src, dst, h, W_edge, b_edge, agg, EE);
        mix_k<<<dim3(NN / NB), blk, 0, stream>>>(flag, agg, W_tower, W_mix, b_mix, mb, NN);
        gru_mfma_k<<<dim3(NN / MB), dim3(192), 0, stream>>>(mb, h, WB, bpack, NN);
    }

    // attention readout
    score_k<<<dim3((NN + 3) / 4), blk, 0, stream>>>(flag, h, W_score, b_score, score, NN);
    zero_k<<<dim3(zgrid_small), blk, 0, stream>>>((float4*)gmax_u, zsmall_n4);
    gmax_k<<<dim3((NN + 255) / 256), blk, 0, stream>>>(score, bv, gmax_u, NN);
    exsum_k<<<dim3((NN + 255) / 256), blk, 0, stream>>>(score, bv, gmax_u, ex, gsum, NN);
    gemm_feat_k<<<dim3(NN / NB), blk, 0, stream>>>(flag, h, W_feat, b_feat, mb, NN);
    scatter_k<<<dim3((NN + NRB - 1) / NRB), blk, 0, stream>>>(mb, ex, gsum, bv, gout, NN);
    final_k<<<dim3(GG), blk, 0, stream>>>(flag, gout, W_r1, b_r1, W_out, b_out, d_out);
}

// Round 5
// 3030.368 us; speedup vs baseline: 2.3159x; 1.6354x over previous
//
#include <hip/hip_runtime.h>
#include <hip/hip_bf16.h>

typedef __hip_bfloat16 bf16;

#define NN  100000   // nodes
#define EE  800000   // edges
#define FN_ 128      // node feature dim
#define FE_ 16       // edge feature dim
#define HN  200      // hidden dim
#define TT  8        // towers
#define DT_ 25       // per-tower dim
#define GG  64       // graphs
#define STEPS_ 3

#define NPB 64       // dst nodes per msg2 block
#define NRB 512      // nodes per scatter block
#define MSTR 400     // bf16 row stride of m/feat overlay inside agg

// MFMA geometry
#define MB   32      // nodes per gru block (2 row-tiles of 16)
#define XSTR 456     // gru LDS X row stride in shorts
#define CTN  13      // col tiles (13*16 = 208 >= 200)
#define KTN  14      // gru k tiles (14*32 = 448 = 224(m) + 224(h))
#define WBSZ (3 * KTN * CTN * 512)   // gru packed weight shorts

typedef __attribute__((ext_vector_type(8))) short short8v;
typedef __attribute__((ext_vector_type(4))) float f32x4;
#define MFMA16(a, b, c) __builtin_amdgcn_mfma_f32_16x16x32_bf16(a, b, c, 0, 0, 0)

__device__ __forceinline__ float b2f(bf16 v) { return __bfloat162float(v); }
__device__ __forceinline__ float us2f(unsigned short u) { return __uint_as_float((unsigned)u << 16); }
__device__ __forceinline__ float sigmf(float x) { return 1.0f / (1.0f + __expf(-x)); }

template <typename T> struct LDR;
template <> struct LDR<bf16> {
    static __device__ __forceinline__ float get(const void* p, size_t i) {
        return __bfloat162float(((const bf16*)p)[i]);
    }
};
template <> struct LDR<float> {
    static __device__ __forceinline__ float get(const void* p, size_t i) {
        return ((const float*)p)[i];
    }
};

__device__ __forceinline__ unsigned ordkey(float x) {
    unsigned b = __float_as_uint(x);
    return b ^ (unsigned)(((int)b >> 31) | (int)0x80000000);
}
__device__ __forceinline__ float ordinv(unsigned u) {
    unsigned b = (u & 0x80000000u) ? (u ^ 0x80000000u) : ~u;
    return __uint_as_float(b);
}

// ---------------- dtype probe ----------------
__global__ __launch_bounds__(256) void probe_k(const void* nf, const void* Win, int* flag) {
    __shared__ int cnt;
    if (threadIdx.x == 0) cnt = 0;
    __syncthreads();
    const unsigned short* a = (const unsigned short*)nf;
    const unsigned short* b = (const unsigned short*)Win;
    int c = 0;
    for (int i = threadIdx.x; i < 2048; i += 256) {
        float x = us2f(a[i]);
        float y = us2f(b[i]);
        if (!(fabsf(x) < 1e3f)) c++;
        if (!(fabsf(y) < 1e3f)) c++;
    }
    atomicAdd(&cnt, c);
    __syncthreads();
    if (threadIdx.x == 0) flag[0] = (cnt >= 8) ? 1 : 0;
}

// ---------------- zero fill ----------------
__global__ __launch_bounds__(256) void zero_k(float4* __restrict__ p, int n4) {
    int i = blockIdx.x * 256 + threadIdx.x;
    if (i < n4) p[i] = float4{0.f, 0.f, 0.f, 0.f};
}

// ---------------- GRU weight pack (3 gates, K=448 fused [W;U]) ----------------
__global__ __launch_bounds__(256) void pack_k(
    const int* flag,
    const void* Wz, const void* Uz, const void* bz,
    const void* Wr, const void* Ur, const void* br,
    const void* Wh, const void* Uh, const void* bh,
    short* __restrict__ WB, float* __restrict__ bpack)
{
    int i = blockIdx.x * 256 + threadIdx.x;
    int f = *flag;
    if (i < WBSZ) {
        int j8 = i & 7;
        int e = i >> 3;
        int lane = e & 63; e >>= 6;
        int ct = e % 13; e /= 13;
        int kt = e % 14;
        int g = e / 14;
        int kl = kt * 32 + (lane >> 4) * 8 + j8;
        int col = ct * 16 + (lane & 15);
        int ksrc = (kl < 224) ? kl : kl - 224;
        const void* W = (kl < 224) ? (g == 0 ? Wz : g == 1 ? Wr : Wh)
                                   : (g == 0 ? Uz : g == 1 ? Ur : Uh);
        float v = 0.f;
        if (ksrc < HN && col < HN)
            v = f ? LDR<float>::get(W, (size_t)ksrc * HN + col)
                  : LDR<bf16>::get(W, (size_t)ksrc * HN + col);
        bf16 t = __float2bfloat16(v);
        WB[i] = *(short*)&t;
    } else {
        int t = i - WBSZ;
        if (t < 3 * 208) {
            int g = t / 208, col = t % 208;
            const void* B = g == 0 ? bz : g == 1 ? br : bh;
            bpack[t] = (col < HN) ? (f ? LDR<float>::get(B, col) : LDR<bf16>::get(B, col)) : 0.f;
        }
    }
}

// ---------------- generic weight pack: [K x HN] -> bf16 B-fragment layout ----------------
__global__ __launch_bounds__(256) void packgen_k(
    const int* flag, const void* W, const void* bias, int K, int KT,
    short* __restrict__ WBo, float* __restrict__ bpo)
{
    int i = blockIdx.x * 256 + threadIdx.x;
    int f = *flag;
    int tot = KT * CTN * 512;
    if (i < tot) {
        int j8 = i & 7;
        int e = i >> 3;
        int lane = e & 63; e >>= 6;
        int ct = e % CTN;
        int kt = e / CTN;
        int kl = kt * 32 + (lane >> 4) * 8 + j8;
        int col = ct * 16 + (lane & 15);
        float v = 0.f;
        if (kl < K && col < HN)
            v = f ? LDR<float>::get(W, (size_t)kl * HN + col)
                  : LDR<bf16>::get(W, (size_t)kl * HN + col);
        bf16 t = __float2bfloat16(v);
        WBo[i] = *(short*)&t;
    } else {
        int t = i - tot;
        if (t < 208) bpo[t] = (t < HN) ? (f ? LDR<float>::get(bias, t) : LDR<bf16>::get(bias, t)) : 0.f;
    }
}

// ---------------- W_eff pack: blockdiag(W_tower) @ W_mix, packed (KT=7) ----------------
__global__ __launch_bounds__(256) void weff_k(
    const int* flag, const void* Wt, const void* Wmix, const void* bmix,
    short* __restrict__ WBo, float* __restrict__ bpo)
{
    int i = blockIdx.x * 256 + threadIdx.x;
    int f = *flag;
    const int tot = 7 * CTN * 512;
    if (i < tot) {
        int j8 = i & 7;
        int e = i >> 3;
        int lane = e & 63; e >>= 6;
        int ct = e % CTN;
        int kt = e / CTN;
        int kl = kt * 32 + (lane >> 4) * 8 + j8;
        int col = ct * 16 + (lane & 15);
        float v = 0.f;
        if (kl < HN && col < HN) {
            int t = kl / DT_, d = kl - t * DT_;
            for (int ee = 0; ee < DT_; ee++) {
                float wt = f ? LDR<float>::get(Wt, (size_t)(t * DT_ + d) * DT_ + ee)
                             : LDR<bf16>::get(Wt, (size_t)(t * DT_ + d) * DT_ + ee);
                float wm = f ? LDR<float>::get(Wmix, (size_t)(t * DT_ + ee) * HN + col)
                             : LDR<bf16>::get(Wmix, (size_t)(t * DT_ + ee) * HN + col);
                v = fmaf(wt, wm, v);
            }
        }
        bf16 tv = __float2bfloat16(v);
        WBo[i] = *(short*)&tv;
    } else {
        int t = i - tot;
        if (t < 208) bpo[t] = (t < HN) ? (f ? LDR<float>::get(bmix, t) : LDR<bf16>::get(bmix, t)) : 0.f;
    }
}

// ---------------- CSR build ----------------
__global__ __launch_bounds__(256) void hist_k(const int* dst, int* cnt, int Ecnt) {
    int e = blockIdx.x * 256 + threadIdx.x;
    if (e < Ecnt) atomicAdd(&cnt[dst[e]], 1);
}

__global__ __launch_bounds__(256) void scan1_k(const int* cnt, int* off, int* part, int Nn) {
    __shared__ int s[256];
    int t = threadIdx.x, i = blockIdx.x * 256 + t;
    int v = (i < Nn) ? cnt[i] : 0;
    s[t] = v; __syncthreads();
    for (int d = 1; d < 256; d <<= 1) {
        int x = (t >= d) ? s[t - d] : 0;
        __syncthreads();
        s[t] += x;
        __syncthreads();
    }
    if (i < Nn) off[i] = s[t] - v;
    if (t == 255) part[blockIdx.x] = s[255];
}

__global__ __launch_bounds__(512) void scan2_k(int* part, int P) {
    __shared__ int s[512];
    int t = threadIdx.x;
    int v = (t < P) ? part[t] : 0;
    s[t] = v; __syncthreads();
    for (int d = 1; d < 512; d <<= 1) {
        int x = (t >= d) ? s[t - d] : 0;
        __syncthreads();
        s[t] += x;
        __syncthreads();
    }
    if (t < P) part[t] = s[t] - v;
}

__global__ __launch_bounds__(256) void scan3_k(const int* part, int* off, int* cursor, int Nn, int Etot) {
    int i = blockIdx.x * 256 + threadIdx.x;
    if (i < Nn) {
        int o = off[i] + part[i >> 8];
        off[i] = o;
        cursor[i] = o;
    }
    if (i == 0) off[Nn] = Etot;
}

__global__ __launch_bounds__(256) void fill_k(
    const int* src, const int* dst, int* cursor, int* srcp, int* eidx, int Ecnt)
{
    int e = blockIdx.x * 256 + threadIdx.x;
    if (e < Ecnt) {
        int p = atomicAdd(&cursor[dst[e]], 1);
        srcp[p] = src[e];
        eidx[p] = e;
    }
}

// ---------------- CSR message pass: no atomics, one write per agg element ----------------
__global__ __launch_bounds__(256) void msg2_k(
    const int* flag, const void* ef, const int* __restrict__ eidx, const int* __restrict__ srcp,
    const int* __restrict__ off, const bf16* __restrict__ h,
    const void* We, const void* be, float* __restrict__ agg, int Nn)
{
    const int tid = threadIdx.x;
    const int n0 = blockIdx.x * NPB;
    if (tid >= HN) return;
    const int f = *flag;
    float wcol[FE_];
#pragma unroll
    for (int k = 0; k < FE_; k++)
        wcol[k] = f ? LDR<float>::get(We, (size_t)k * HN + tid) : LDR<bf16>::get(We, (size_t)k * HN + tid);
    float bj = f ? LDR<float>::get(be, tid) : LDR<bf16>::get(be, tid);

    for (int dd = 0; dd < NPB; dd++) {
        int d = n0 + dd;
        if (d >= Nn) break;
        int i0 = off[d], i1 = off[d + 1];
        float a = 0.f;
        for (int i = i0; i < i1; i++) {
            int e = eidx[i];
            int s = srcp[i];
            float g = bj;
            if (f) {
                const float* er = (const float*)ef + (size_t)e * FE_;
#pragma unroll
                for (int k = 0; k < FE_; k++) g = fmaf(er[k], wcol[k], g);
            } else {
                const bf16* er = (const bf16*)ef + (size_t)e * FE_;
#pragma unroll
                for (int k = 0; k < FE_; k++) g = fmaf(b2f(er[k]), wcol[k], g);
            }
            g = sigmf(g);
            a = fmaf(g, b2f(h[(size_t)s * HN + tid]), a);
        }
        agg[(size_t)d * HN + tid] = a;
    }
}

// ---------------- generic MFMA GEMM: out = act(X @ WBp + bp), 32 rows/block, 2 waves ----------------
__global__ __launch_bounds__(128) void gemmm_k(
    const int* flag, int xmode, const void* X, int K, int xstride, int KT,
    const short* __restrict__ WBp, const float* __restrict__ bp, int relu,
    bf16* __restrict__ out, int ostride, int Nn)
{
    __shared__ unsigned short Xs[32][232];
    const int tid = threadIdx.x;
    const int w = tid >> 6, lane = tid & 63;
    const int qd = lane >> 4, c0 = lane & 15;
    const int n0 = blockIdx.x * 32;
    const int xf32 = (xmode == 2) ? *flag : xmode;
    const int chunks = (KT * 32) >> 2;

    for (int i = tid; i < 32 * chunks; i += 128) {
        int row = i / chunks, c4 = (i - row * chunks) << 2;
        int grow = n0 + row;
        ushort4 v = ushort4{0, 0, 0, 0};
        if (grow < Nn && c4 < K) {   // K % 4 == 0 in all uses
            if (xf32) {
                const float* xr = (const float*)X + (size_t)grow * xstride + c4;
                float4 fv = *(const float4*)xr;
                bf16 b0 = __float2bfloat16(fv.x), b1 = __float2bfloat16(fv.y);
                bf16 b2 = __float2bfloat16(fv.z), b3 = __float2bfloat16(fv.w);
                v = ushort4{*(unsigned short*)&b0, *(unsigned short*)&b1,
                            *(unsigned short*)&b2, *(unsigned short*)&b3};
            } else {
                v = *(const ushort4*)((const bf16*)X + (size_t)grow * xstride + c4);
            }
        }
        *(ushort4*)&Xs[row][c4] = v;
    }
    __syncthreads();

    const int ct0 = w * 7;
    const int ctn = w ? (CTN - 7) : 7;
    f32x4 acc[2][7];
#pragma unroll
    for (int mt = 0; mt < 2; mt++)
#pragma unroll
        for (int ctl = 0; ctl < 7; ctl++)
            acc[mt][ctl] = f32x4{0.f, 0.f, 0.f, 0.f};

    for (int kt = 0; kt < KT; kt++) {
        short8v a0 = *(const short8v*)&Xs[c0][kt * 32 + qd * 8];
        short8v a1 = *(const short8v*)&Xs[16 + c0][kt * 32 + qd * 8];
        const short* wp = WBp + ((size_t)kt * CTN + ct0) * 512 + lane * 8;
#pragma unroll
        for (int ctl = 0; ctl < 7; ctl++) {
            if (ctl < ctn) {
                short8v b = *(const short8v*)(wp + (size_t)ctl * 512);
                acc[0][ctl] = MFMA16(a0, b, acc[0][ctl]);
                acc[1][ctl] = MFMA16(a1, b, acc[1][ctl]);
            }
        }
    }

#pragma unroll
    for (int mt = 0; mt < 2; mt++)
#pragma unroll
        for (int ctl = 0; ctl < 7; ctl++) {
            if (ctl < ctn) {
#pragma unroll
                for (int r = 0; r < 4; r++) {
                    int row = n0 + mt * 16 + qd * 4 + r;
                    int col = (ct0 + ctl) * 16 + c0;
                    if (row < Nn && col < HN) {
                        float v = acc[mt][ctl][r] + bp[col];
                        if (relu) v = fmaxf(v, 0.f);
                        out[(size_t)row * ostride + col] = __float2bfloat16(v);
                    }
                }
            }
        }
}

// ---------------- MFMA GRU: 3 waves (z | r | h~), in-place h update ----------------
__global__ __launch_bounds__(192) void gru_mfma_k(
    const bf16* __restrict__ mb, bf16* __restrict__ h,
    const short* __restrict__ WB, const float* __restrict__ bpack, int Nn)
{
    __shared__ unsigned short Xs[MB][XSTR];
    __shared__ float zbuf[MB][CTN * 16];
    const int tid = threadIdx.x;
    const int g = tid >> 6, lane = tid & 63;
    const int qd = lane >> 4, c0 = lane & 15;
    const int n0 = blockIdx.x * MB;

    for (int i = tid; i < MB * (XSTR / 4); i += 192) {
        int row = i / (XSTR / 4);
        int c4 = (i - row * (XSTR / 4)) * 4;
        ushort4 v = ushort4{0, 0, 0, 0};
        if (c4 < HN)
            v = *(const ushort4*)&mb[(size_t)(n0 + row) * MSTR + c4];
        else if (c4 >= 224 && c4 < 224 + HN)
            v = *(const ushort4*)&h[(size_t)(n0 + row) * HN + (c4 - 224)];
        *(ushort4*)&Xs[row][c4] = v;
    }
    __syncthreads();

    f32x4 acc[2][CTN];
#pragma unroll
    for (int mt = 0; mt < 2; mt++)
#pragma unroll
        for (int ct = 0; ct < CTN; ct++)
            acc[mt][ct] = f32x4{0.f, 0.f, 0.f, 0.f};

    const int ktEnd = (g == 2) ? 7 : KTN;
    for (int kt = 0; kt < ktEnd; kt++) {
        short8v a0 = *(const short8v*)&Xs[c0][kt * 32 + qd * 8];
        short8v a1 = *(const short8v*)&Xs[16 + c0][kt * 32 + qd * 8];
        const short* wp = WB + (size_t)(g * KTN + kt) * CTN * 512 + lane * 8;
#pragma unroll
        for (int ct = 0; ct < CTN; ct++) {
            short8v b = *(const short8v*)(wp + (size_t)ct * 512);
            acc[0][ct] = MFMA16(a0, b, acc[0][ct]);
            acc[1][ct] = MFMA16(a1, b, acc[1][ct]);
        }
    }
    __syncthreads();

    if (g == 0) {
#pragma unroll
        for (int mt = 0; mt < 2; mt++)
#pragma unroll
            for (int ct = 0; ct < CTN; ct++)
#pragma unroll
                for (int r = 0; r < 4; r++) {
                    int row = mt * 16 + qd * 4 + r;
                    int col = ct * 16 + c0;
                    zbuf[row][col] = sigmf(acc[mt][ct][r] + bpack[col]);
                }
    } else if (g == 1) {
#pragma unroll
        for (int mt = 0; mt < 2; mt++)
#pragma unroll
            for (int ct = 0; ct < CTN; ct++)
#pragma unroll
                for (int r = 0; r < 4; r++) {
                    int row = mt * 16 + qd * 4 + r;
                    int col = ct * 16 + c0;
                    float rr = sigmf(acc[mt][ct][r] + bpack[208 + col]);
                    float hv = us2f(Xs[row][224 + col]);
                    bf16 t = __float2bfloat16(rr * hv);
                    Xs[row][224 + col] = *(unsigned short*)&t;
                }
    }
    __syncthreads();

    if (g == 2) {
        for (int kt = 7; kt < KTN; kt++) {
            short8v a0 = *(const short8v*)&Xs[c0][kt * 32 + qd * 8];
            short8v a1 = *(const short8v*)&Xs[16 + c0][kt * 32 + qd * 8];
            const short* wp = WB + (size_t)(2 * KTN + kt) * CTN * 512 + lane * 8;
#pragma unroll
            for (int ct = 0; ct < CTN; ct++) {
                short8v b = *(const short8v*)(wp + (size_t)ct * 512);
                acc[0][ct] = MFMA16(a0, b, acc[0][ct]);
                acc[1][ct] = MFMA16(a1, b, acc[1][ct]);
            }
        }
#pragma unroll
        for (int mt = 0; mt < 2; mt++)
#pragma unroll
            for (int ct = 0; ct < CTN; ct++)
#pragma unroll
                for (int r = 0; r < 4; r++) {
                    int row = mt * 16 + qd * 4 + r;
                    int col = ct * 16 + c0;
                    if (col < HN) {
                        float ah = acc[mt][ct][r] + bpack[416 + col];
                        ah = fminf(fmaxf(ah, -15.f), 15.f);
                        float e = __expf(2.f * ah);
                        float htl = (e - 1.f) / (e + 1.f);
                        size_t idx = (size_t)(n0 + row) * HN + col;
                        float hv = b2f(h[idx]);
                        h[idx] = __float2bfloat16(fmaf(zbuf[row][col], htl - hv, hv));
                    }
                }
    }
}

// ---------------- attention score ----------------
template <typename T>
__device__ __forceinline__ void score_impl(
    const bf16* h, const void* Ws, const void* bs, float* score, int Nn, int node, int lane)
{
    if (node >= Nn) return;
    float a = 0.f;
    for (int k = lane; k < HN; k += 64) a = fmaf(b2f(h[(size_t)node * HN + k]), LDR<T>::get(Ws, k), a);
    for (int off = 32; off; off >>= 1) a += __shfl_down(a, off, 64);
    if (lane == 0) score[node] = a + LDR<T>::get(bs, 0);
}

__global__ __launch_bounds__(256) void score_k(
    const int* flag, const bf16* h, const void* Ws, const void* bs, float* score, int Nn)
{
    int node = blockIdx.x * 4 + (threadIdx.x >> 6);
    int lane = threadIdx.x & 63;
    if (*flag) score_impl<float>(h, Ws, bs, score, Nn, node, lane);
    else       score_impl<bf16>(h, Ws, bs, score, Nn, node, lane);
}

// ---------------- segment max ----------------
__global__ __launch_bounds__(256) void gmax_k(
    const float* __restrict__ score, const int* __restrict__ bv,
    unsigned* __restrict__ gmax_u, int Nn)
{
    __shared__ unsigned lm[GG];
    const int tid = threadIdx.x;
    for (int i = tid; i < GG; i += 256) lm[i] = 0u;
    __syncthreads();
    int n = blockIdx.x * 256 + tid;
    if (n < Nn) atomicMax(&lm[bv[n]], ordkey(score[n]));
    __syncthreads();
    for (int i = tid; i < GG; i += 256)
        if (lm[i]) atomicMax(&gmax_u[i], lm[i]);
}

// ---------------- exp + segment sum ----------------
__global__ __launch_bounds__(256) void exsum_k(
    const float* __restrict__ score, const int* __restrict__ bv,
    const unsigned* __restrict__ gmax_u, float* __restrict__ ex,
    float* __restrict__ gsum, int Nn)
{
    __shared__ float ls[GG];
    const int tid = threadIdx.x;
    for (int i = tid; i < GG; i += 256) ls[i] = 0.f;
    __syncthreads();
    int n = blockIdx.x * 256 + tid;
    if (n < Nn) {
        int g = bv[n];
        float e = __expf(score[n] - ordinv(gmax_u[g]));
        ex[n] = e;
        atomicAdd(&ls[g], e);
    }
    __syncthreads();
    for (int i = tid; i < GG; i += 256)
        if (ls[i] != 0.f) atomicAdd(&gsum[i], ls[i]);
}

// ---------------- weighted readout scatter ----------------
__global__ __launch_bounds__(256) void scatter_k(
    const bf16* __restrict__ feat, const float* __restrict__ ex,
    const float* __restrict__ gsum, const int* __restrict__ bv,
    float* __restrict__ gout, int Nn)
{
    const int tid = threadIdx.x;
    if (tid >= HN) return;
    int n0 = blockIdx.x * NRB;
    int lim = Nn - n0; if (lim > NRB) lim = NRB;
    float acc = 0.f;
    int cur = -1;
    float inv = 0.f;
    for (int i = 0; i < lim; i++) {
        int n = n0 + i;
        int g = bv[n];
        if (g != cur) {
            if (cur >= 0) atomicAdd(&gout[cur * HN + tid], acc);
            acc = 0.f;
            cur = g;
            inv = 1.0f / gsum[g];
        }
        acc = fmaf(ex[n] * inv, b2f(feat[(size_t)n * MSTR + tid]), acc);
    }
    if (cur >= 0) atomicAdd(&gout[cur * HN + tid], acc);
}

// ---------------- readout MLP ----------------
template <typename T, int OUTF32>
__device__ __forceinline__ void final_impl(
    float* r1s, const float* gout,
    const void* Wr1, const void* br1, const void* Wout, const void* bout,
    void* out, int g, int tid)
{
    if (tid < HN) {
        float v = LDR<T>::get(br1, tid);
        for (int k = 0; k < HN; k++) v = fmaf(gout[g * HN + k], LDR<T>::get(Wr1, (size_t)k * HN + tid), v);
        r1s[tid] = (v == v) ? fmaxf(v, 0.f) : v;
    }
    __syncthreads();
    if (tid < 64) {
        float a = 0.f;
        for (int k = tid; k < HN; k += 64) a = fmaf(r1s[k], LDR<T>::get(Wout, k), a);
        for (int off = 32; off; off >>= 1) a += __shfl_down(a, off, 64);
        if (tid == 0) {
            float res = a + LDR<T>::get(bout, 0);
            if (OUTF32) ((float*)out)[g] = res;
            else        ((bf16*)out)[g] = __float2bfloat16(res);
        }
    }
}

__global__ __launch_bounds__(256) void final_k(
    const int* flag, const float* gout,
    const void* Wr1, const void* br1, const void* Wout, const void* bout, void* out)
{
    __shared__ float r1s[HN];
    const int g = blockIdx.x, tid = threadIdx.x;
    if (*flag) final_impl<float, 1>(r1s, gout, Wr1, br1, Wout, bout, out, g, tid);
    else       final_impl<bf16,  0>(r1s, gout, Wr1, br1, Wout, bout, out, g, tid);
}

extern "C" void kernel_launch(void* const* d_in, const int* in_sizes, int n_in,
                              void* d_out, int out_size, void* d_ws, size_t ws_size,
                              hipStream_t stream)
{
    const void* nf      = d_in[0];
    const void* ef      = d_in[1];
    const int*  ei      = (const int*)d_in[2];
    const int*  bv      = (const int*)d_in[3];
    const void* W_in    = d_in[4];
    const void* b_in    = d_in[5];
    const void* W_edge  = d_in[6];
    const void* b_edge  = d_in[7];
    const void* W_tower = d_in[8];
    const void* W_mix   = d_in[9];
    const void* b_mix   = d_in[10];
    const void* Wz      = d_in[11];
    const void* Uz      = d_in[12];
    const void* bz      = d_in[13];
    const void* Wr      = d_in[14];
    const void* Ur      = d_in[15];
    const void* br      = d_in[16];
    const void* Wh      = d_in[17];
    const void* Uh      = d_in[18];
    const void* bh      = d_in[19];
    const void* W_score = d_in[20];
    const void* b_score = d_in[21];
    const void* W_feat  = d_in[22];
    const void* b_feat  = d_in[23];
    const void* W_r1    = d_in[24];
    const void* b_r1    = d_in[25];
    const void* W_out   = d_in[26];
    const void* b_out   = d_in[27];

    const int* src = ei;
    const int* dst = ei + EE;

    // ---- workspace layout (~130 MB) ----
    const size_t NH = (size_t)NN * HN;
    char* p = (char*)d_ws;
    auto take = [&](size_t bytes) { char* r = p; p += (bytes + 15) & ~(size_t)15; return r; };
    bf16*  h      = (bf16*)take(NH * 2);
    float* agg    = (float*)take(NH * 4);
    bf16*  mb     = (bf16*)agg;            // overlay, row stride MSTR
    float* score  = (float*)take(NN * 4);
    float* ex     = (float*)take(NN * 4);
    unsigned* gmax_u = (unsigned*)take((GG + GG + GG * HN) * 4);  // gmax | gsum | gout contiguous
    float* gsum   = (float*)(gmax_u + GG);
    float* gout   = gsum + GG;
    short* WB     = (short*)take(WBSZ * 2);
    float* bpack  = (float*)take(3 * 208 * 4);
    short* WBmix  = (short*)take(7 * CTN * 512 * 2);
    float* bpmix  = (float*)take(208 * 4);
    short* WBfeat = (short*)take(7 * CTN * 512 * 2);
    float* bpfeat = (float*)take(208 * 4);
    short* WBin   = (short*)take(4 * CTN * 512 * 2);
    float* bpin   = (float*)take(208 * 4);
    int*   cnt    = (int*)take(NN * 4);
    int*   off    = (int*)take((NN + 1) * 4);
    int*   cursor = (int*)take(NN * 4);
    int*   part   = (int*)take(512 * 4);
    int*   srcp   = (int*)take(EE * 4);
    int*   eidx   = (int*)take(EE * 4);
    int*   flag   = (int*)take(16);

    const dim3 blk(256);
    const int zsmall_n4 = (GG + GG + GG * HN) / 4;

    probe_k<<<dim3(1), blk, 0, stream>>>(nf, W_in, flag);

    // weight packs (once per launch)
    pack_k<<<dim3((WBSZ + 3 * 208 + 255) / 256), blk, 0, stream>>>(
        flag, Wz, Uz, bz, Wr, Ur, br, Wh, Uh, bh, WB, bpack);
    weff_k<<<dim3((7 * CTN * 512 + 208 + 255) / 256), blk, 0, stream>>>(
        flag, W_tower, W_mix, b_mix, WBmix, bpmix);
    packgen_k<<<dim3((7 * CTN * 512 + 208 + 255) / 256), blk, 0, stream>>>(
        flag, W_feat, b_feat, HN, 7, WBfeat, bpfeat);
    packgen_k<<<dim3((4 * CTN * 512 + 208 + 255) / 256), blk, 0, stream>>>(
        flag, W_in, b_in, FN_, 4, WBin, bpin);

    // CSR build (once per launch)
    zero_k<<<dim3((NN / 4 + 255) / 256), blk, 0, stream>>>((float4*)cnt, NN / 4);
    hist_k<<<dim3(EE / 256), blk, 0, stream>>>(dst, cnt, EE);
    const int SB = (NN + 255) / 256;   // 391
    scan1_k<<<dim3(SB), blk, 0, stream>>>(cnt, off, part, NN);
    scan2_k<<<dim3(1), dim3(512), 0, stream>>>(part, SB);
    scan3_k<<<dim3(SB), blk, 0, stream>>>(part, off, cursor, NN, EE);
    fill_k<<<dim3(EE / 256), blk, 0, stream>>>(src, dst, cursor, srcp, eidx, EE);

    // h = relu(nf @ W_in + b_in)
    gemmm_k<<<dim3(NN / 32), dim3(128), 0, stream>>>(
        flag, 2, nf, FN_, FN_, 4, WBin, bpin, 1, h, HN, NN);

    for (int s = 0; s < STEPS_; s++) {
        msg2_k<<<dim3((NN + NPB - 1) / NPB), blk, 0, stream>>>(
            flag, ef, eidx, srcp, off, h, W_edge, b_edge, agg, NN);
        gemmm_k<<<dim3(NN / 32), dim3(128), 0, stream>>>(
            flag, 1, agg, HN, HN, 7, WBmix, bpmix, 1, mb, MSTR, NN);
        gru_mfma_k<<<dim3(NN / MB), dim3(192), 0, stream>>>(mb, h, WB, bpack, NN);
    }

    // attention readout
    score_k<<<dim3((NN + 3) / 4), blk, 0, stream>>>(flag, h, W_score, b_score, score, NN);
    zero_k<<<dim3((zsmall_n4 + 255) / 256), blk, 0, stream>>>((float4*)gmax_u, zsmall_n4);
    gmax_k<<<dim3((NN + 255) / 256), blk, 0, stream>>>(score, bv, gmax_u, NN);
    exsum_k<<<dim3((NN + 255) / 256), blk, 0, stream>>>(score, bv, gmax_u, ex, gsum, NN);
    gemmm_k<<<dim3(NN / 32), dim3(128), 0, stream>>>(
        flag, 0, h, HN, HN, 7, WBfeat, bpfeat, 0, mb, MSTR, NN);
    scatter_k<<<dim3((NN + NRB - 1) / NRB), blk, 0, stream>>>(mb, ex, gsum, bv, gout, NN);
    final_k<<<dim3(GG), blk, 0, stream>>>(flag, gout, W_r1, b_r1, W_out, b_out, d_out);
}

// Round 6
// 2668.155 us; speedup vs baseline: 2.6303x; 1.1358x over previous
//
#include <hip/hip_runtime.h>
#include <hip/hip_bf16.h>

typedef __hip_bfloat16 bf16;

#define NN  100000   // nodes
#define EE  800000   // edges
#define FN_ 128      // node feature dim
#define FE_ 16       // edge feature dim
#define HN  200      // hidden dim
#define TT  8        // towers
#define DT_ 25       // per-tower dim
#define GG  64       // graphs
#define STEPS_ 3

#define NPB 64       // dst nodes per msg block
#define NRB 512      // nodes per scatter block

// MFMA geometry
#define MB   32      // nodes per gru block (2 row-tiles of 16)
#define XSTR 456     // gru LDS X row stride in shorts
#define CTN  13      // col tiles (13*16 = 208 >= 200)
#define KTN  14      // gru k tiles (14*32 = 448 = 224(m) + 224(h))
#define WBSZ (3 * KTN * CTN * 512)   // gru packed weight shorts

// pack_all region sizes
#define PA_A (WBSZ + 3 * 208)
#define PA_B (7 * CTN * 512 + 208)
#define PA_C (7 * CTN * 512 + 208)
#define PA_D (4 * CTN * 512 + 208)
#define PA_E (FE_ * HN + HN)
#define PA_TOT (PA_A + PA_B + PA_C + PA_D + PA_E)

typedef __attribute__((ext_vector_type(8))) short short8v;
typedef __attribute__((ext_vector_type(4))) float f32x4;
#define MFMA16(a, b, c) __builtin_amdgcn_mfma_f32_16x16x32_bf16(a, b, c, 0, 0, 0)

__device__ __forceinline__ float b2f(bf16 v) { return __bfloat162float(v); }
__device__ __forceinline__ float us2f(unsigned short u) { return __uint_as_float((unsigned)u << 16); }
__device__ __forceinline__ unsigned short f2us(float x) { bf16 t = __float2bfloat16(x); return *(unsigned short*)&t; }
__device__ __forceinline__ float sigmf(float x) { return 1.0f / (1.0f + __expf(-x)); }

template <typename T> struct LDR;
template <> struct LDR<bf16> {
    static __device__ __forceinline__ float get(const void* p, size_t i) {
        return __bfloat162float(((const bf16*)p)[i]);
    }
};
template <> struct LDR<float> {
    static __device__ __forceinline__ float get(const void* p, size_t i) {
        return ((const float*)p)[i];
    }
};
__device__ __forceinline__ float ldsel(const void* p, size_t i, int f) {
    return f ? LDR<float>::get(p, i) : LDR<bf16>::get(p, i);
}

__device__ __forceinline__ unsigned ordkey(float x) {
    unsigned b = __float_as_uint(x);
    return b ^ (unsigned)(((int)b >> 31) | (int)0x80000000);
}
__device__ __forceinline__ float ordinv(unsigned u) {
    unsigned b = (u & 0x80000000u) ? (u ^ 0x80000000u) : ~u;
    return __uint_as_float(b);
}

// ---------------- dtype probe ----------------
__global__ __launch_bounds__(256) void probe_k(const void* nf, const void* Win, int* flag) {
    __shared__ int cnt;
    if (threadIdx.x == 0) cnt = 0;
    __syncthreads();
    const unsigned short* a = (const unsigned short*)nf;
    const unsigned short* b = (const unsigned short*)Win;
    int c = 0;
    for (int i = threadIdx.x; i < 2048; i += 256) {
        float x = us2f(a[i]);
        float y = us2f(b[i]);
        if (!(fabsf(x) < 1e3f)) c++;
        if (!(fabsf(y) < 1e3f)) c++;
    }
    atomicAdd(&cnt, c);
    __syncthreads();
    if (threadIdx.x == 0) flag[0] = (cnt >= 8) ? 1 : 0;
}

// ---------------- zero fill ----------------
__global__ __launch_bounds__(256) void zero_k(float4* __restrict__ p, int n4) {
    int i = blockIdx.x * 256 + threadIdx.x;
    if (i < n4) p[i] = float4{0.f, 0.f, 0.f, 0.f};
}

// ---------------- ALL weight packs in one kernel ----------------
__global__ __launch_bounds__(256) void pack_all_k(
    const int* flag,
    const void* Wz, const void* Uz, const void* bz,
    const void* Wr, const void* Ur, const void* br,
    const void* Wh, const void* Uh, const void* bh,
    const void* Wt, const void* Wmix, const void* bmix,
    const void* Wfeat, const void* bfeat, const void* Wscore, const void* bscore,
    const void* Win, const void* bin,
    const void* Wedge, const void* bedge,
    short* __restrict__ WB, float* __restrict__ bpack,
    short* __restrict__ WBmix, float* __restrict__ bpmix,
    short* __restrict__ WBfs, float* __restrict__ bpfs,
    short* __restrict__ WBin, float* __restrict__ bpin,
    float* __restrict__ Wef, float* __restrict__ bef)
{
    int i = blockIdx.x * 256 + threadIdx.x;
    const int f = *flag;

    if (i < PA_A) {                       // ---- region A: GRU gates [W;U] K=448
        if (i < WBSZ) {
            int j8 = i & 7;
            int e = i >> 3;
            int lane = e & 63; e >>= 6;
            int ct = e % 13; e /= 13;
            int kt = e % 14;
            int g = e / 14;
            int kl = kt * 32 + (lane >> 4) * 8 + j8;
            int col = ct * 16 + (lane & 15);
            int ksrc = (kl < 224) ? kl : kl - 224;
            const void* W = (kl < 224) ? (g == 0 ? Wz : g == 1 ? Wr : Wh)
                                       : (g == 0 ? Uz : g == 1 ? Ur : Uh);
            float v = 0.f;
            if (ksrc < HN && col < HN) v = ldsel(W, (size_t)ksrc * HN + col, f);
            WB[i] = (short)f2us(v);
        } else {
            int t = i - WBSZ;
            int g = t / 208, col = t % 208;
            const void* B = g == 0 ? bz : g == 1 ? br : bh;
            bpack[t] = (col < HN) ? ldsel(B, col, f) : 0.f;
        }
        return;
    }
    i -= PA_A;
    if (i < PA_B) {                       // ---- region B: W_eff = blockdiag(W_tower)@W_mix
        const int tot = 7 * CTN * 512;
        if (i < tot) {
            int j8 = i & 7;
            int e = i >> 3;
            int lane = e & 63; e >>= 6;
            int ct = e % CTN;
            int kt = e / CTN;
            int kl = kt * 32 + (lane >> 4) * 8 + j8;
            int col = ct * 16 + (lane & 15);
            float v = 0.f;
            if (kl < HN && col < HN) {
                int t = kl / DT_, d = kl - t * DT_;
                for (int ee = 0; ee < DT_; ee++) {
                    float wt = ldsel(Wt, (size_t)(t * DT_ + d) * DT_ + ee, f);
                    float wm = ldsel(Wmix, (size_t)(t * DT_ + ee) * HN + col, f);
                    v = fmaf(wt, wm, v);
                }
            }
            WBmix[i] = (short)f2us(v);
        } else {
            int t = i - tot;
            bpmix[t] = (t < HN) ? ldsel(bmix, t, f) : 0.f;
        }
        return;
    }
    i -= PA_B;
    if (i < PA_C) {                       // ---- region C: W_feat with W_score as col 200
        const int tot = 7 * CTN * 512;
        if (i < tot) {
            int j8 = i & 7;
            int e = i >> 3;
            int lane = e & 63; e >>= 6;
            int ct = e % CTN;
            int kt = e / CTN;
            int kl = kt * 32 + (lane >> 4) * 8 + j8;
            int col = ct * 16 + (lane & 15);
            float v = 0.f;
            if (kl < HN) {
                if (col < HN) v = ldsel(Wfeat, (size_t)kl * HN + col, f);
                else if (col == HN) v = ldsel(Wscore, kl, f);
            }
            WBfs[i] = (short)f2us(v);
        } else {
            int t = i - tot;
            float v = 0.f;
            if (t < HN) v = ldsel(bfeat, t, f);
            else if (t == HN) v = ldsel(bscore, 0, f);
            bpfs[t] = v;
        }
        return;
    }
    i -= PA_C;
    if (i < PA_D) {                       // ---- region D: W_in (K=128)
        const int tot = 4 * CTN * 512;
        if (i < tot) {
            int j8 = i & 7;
            int e = i >> 3;
            int lane = e & 63; e >>= 6;
            int ct = e % CTN;
            int kt = e / CTN;
            int kl = kt * 32 + (lane >> 4) * 8 + j8;
            int col = ct * 16 + (lane & 15);
            float v = 0.f;
            if (kl < FN_ && col < HN) v = ldsel(Win, (size_t)kl * HN + col, f);
            WBin[i] = (short)f2us(v);
        } else {
            int t = i - tot;
            bpin[t] = (t < HN) ? ldsel(bin, t, f) : 0.f;
        }
        return;
    }
    i -= PA_D;
    if (i < PA_E) {                       // ---- region E: W_edge as f32 + b_edge
        if (i < FE_ * HN) Wef[i] = ldsel(Wedge, i, f);
        else bef[i - FE_ * HN] = ldsel(bedge, i - FE_ * HN, f);
    }
}

// ---------------- CSR build ----------------
__global__ __launch_bounds__(256) void hist_k(const int* dst, int* cnt, int Ecnt) {
    int e = blockIdx.x * 256 + threadIdx.x;
    if (e < Ecnt) atomicAdd(&cnt[dst[e]], 1);
}

__global__ __launch_bounds__(256) void scan1_k(const int* cnt, int* off, int* part, int Nn) {
    __shared__ int s[256];
    int t = threadIdx.x, i = blockIdx.x * 256 + t;
    int v = (i < Nn) ? cnt[i] : 0;
    s[t] = v; __syncthreads();
    for (int d = 1; d < 256; d <<= 1) {
        int x = (t >= d) ? s[t - d] : 0;
        __syncthreads();
        s[t] += x;
        __syncthreads();
    }
    if (i < Nn) off[i] = s[t] - v;
    if (t == 255) part[blockIdx.x] = s[255];
}

__global__ __launch_bounds__(512) void scan2_k(int* part, int P) {
    __shared__ int s[512];
    int t = threadIdx.x;
    int v = (t < P) ? part[t] : 0;
    s[t] = v; __syncthreads();
    for (int d = 1; d < 512; d <<= 1) {
        int x = (t >= d) ? s[t - d] : 0;
        __syncthreads();
        s[t] += x;
        __syncthreads();
    }
    if (t < P) part[t] = s[t] - v;
}

__global__ __launch_bounds__(256) void scan3_k(const int* part, int* off, int* cursor, int Nn, int Etot) {
    int i = blockIdx.x * 256 + threadIdx.x;
    if (i < Nn) {
        int o = off[i] + part[i >> 8];
        off[i] = o;
        cursor[i] = o;
    }
    if (i == 0) off[Nn] = Etot;
}

__global__ __launch_bounds__(256) void fill_k(
    const int* src, const int* dst, int* cursor, int* srcp, int* eidx, int Ecnt)
{
    int e = blockIdx.x * 256 + threadIdx.x;
    if (e < Ecnt) {
        int p = atomicAdd(&cursor[dst[e]], 1);
        srcp[p] = src[e];
        eidx[p] = e;
    }
}

// ---------------- permute ef rows into CSR order as bf16 ----------------
__global__ __launch_bounds__(256) void permute_k(
    const int* flag, const void* ef, const int* __restrict__ eidx,
    bf16* __restrict__ efp, int Ecnt)
{
    int i = blockIdx.x * 256 + threadIdx.x;
    if (i >= Ecnt) return;
    int e = eidx[i];
    unsigned short row[16];
    if (*flag) {
        const float* er = (const float*)ef + (size_t)e * FE_;
#pragma unroll
        for (int k = 0; k < FE_; k++) row[k] = f2us(er[k]);
    } else {
        const unsigned short* er = (const unsigned short*)ef + (size_t)e * FE_;
#pragma unroll
        for (int k = 0; k < FE_; k++) row[k] = er[k];
    }
    ushort4* o = (ushort4*)(efp + (size_t)i * FE_);
#pragma unroll
    for (int q = 0; q < 4; q++)
        o[q] = ushort4{row[4 * q], row[4 * q + 1], row[4 * q + 2], row[4 * q + 3]};
}

// ---------------- CSR message pass v3: streamed efp, 4-edge unroll ----------------
__global__ __launch_bounds__(256) void msg3_k(
    const bf16* __restrict__ efp, const int* __restrict__ srcp,
    const int* __restrict__ off, const bf16* __restrict__ h,
    const float* __restrict__ Wef, const float* __restrict__ bef,
    bf16* __restrict__ aggb, int Nn)
{
    const int tid = threadIdx.x;
    if (tid >= HN) return;
    const int n0 = blockIdx.x * NPB;
    float wcol[FE_];
#pragma unroll
    for (int k = 0; k < FE_; k++) wcol[k] = Wef[k * HN + tid];
    const float bj = bef[tid];

    for (int dd = 0; dd < NPB; dd++) {
        int d = n0 + dd;
        if (d >= Nn) break;
        int i0 = off[d], i1 = off[d + 1];
        float a = 0.f;
        int i = i0;
        for (; i + 4 <= i1; i += 4) {
            int s0 = srcp[i], s1 = srcp[i + 1], s2 = srcp[i + 2], s3 = srcp[i + 3];
            const short8v* fr = (const short8v*)(efp + (size_t)i * FE_);
            short8v fa0 = fr[0], fb0 = fr[1], fa1 = fr[2], fb1 = fr[3];
            short8v fa2 = fr[4], fb2 = fr[5], fa3 = fr[6], fb3 = fr[7];
            unsigned short h0 = *(const unsigned short*)&h[(size_t)s0 * HN + tid];
            unsigned short h1 = *(const unsigned short*)&h[(size_t)s1 * HN + tid];
            unsigned short h2 = *(const unsigned short*)&h[(size_t)s2 * HN + tid];
            unsigned short h3 = *(const unsigned short*)&h[(size_t)s3 * HN + tid];
            float g0 = bj, g1 = bj, g2 = bj, g3 = bj;
#pragma unroll
            for (int k = 0; k < 8; k++) {
                g0 = fmaf(us2f((unsigned short)fa0[k]), wcol[k], g0);
                g1 = fmaf(us2f((unsigned short)fa1[k]), wcol[k], g1);
                g2 = fmaf(us2f((unsigned short)fa2[k]), wcol[k], g2);
                g3 = fmaf(us2f((unsigned short)fa3[k]), wcol[k], g3);
            }
#pragma unroll
            for (int k = 0; k < 8; k++) {
                g0 = fmaf(us2f((unsigned short)fb0[k]), wcol[8 + k], g0);
                g1 = fmaf(us2f((unsigned short)fb1[k]), wcol[8 + k], g1);
                g2 = fmaf(us2f((unsigned short)fb2[k]), wcol[8 + k], g2);
                g3 = fmaf(us2f((unsigned short)fb3[k]), wcol[8 + k], g3);
            }
            a = fmaf(sigmf(g0), us2f(h0), a);
            a = fmaf(sigmf(g1), us2f(h1), a);
            a = fmaf(sigmf(g2), us2f(h2), a);
            a = fmaf(sigmf(g3), us2f(h3), a);
        }
        for (; i < i1; i++) {
            int s = srcp[i];
            const short8v* fr = (const short8v*)(efp + (size_t)i * FE_);
            short8v fa = fr[0], fb = fr[1];
            float g = bj;
#pragma unroll
            for (int k = 0; k < 8; k++) g = fmaf(us2f((unsigned short)fa[k]), wcol[k], g);
#pragma unroll
            for (int k = 0; k < 8; k++) g = fmaf(us2f((unsigned short)fb[k]), wcol[8 + k], g);
            a = fmaf(sigmf(g), b2f(h[(size_t)s * HN + tid]), a);
        }
        aggb[(size_t)d * HN + tid] = __float2bfloat16(a);
    }
}

// ---------------- generic MFMA GEMM (+optional fused score col 200) ----------------
__global__ __launch_bounds__(128) void gemmm_k(
    const int* flag, int xmode, const void* X, int K, int xstride, int KT,
    const short* __restrict__ WBp, const float* __restrict__ bp, int relu,
    bf16* __restrict__ out, int ostride, float* __restrict__ scoreOut, int Nn)
{
    __shared__ unsigned short Xs[32][232];
    const int tid = threadIdx.x;
    const int w = tid >> 6, lane = tid & 63;
    const int qd = lane >> 4, c0 = lane & 15;
    const int n0 = blockIdx.x * 32;
    const int xf32 = (xmode == 2) ? *flag : xmode;
    const int chunks = (KT * 32) >> 2;

    for (int i = tid; i < 32 * chunks; i += 128) {
        int row = i / chunks, c4 = (i - row * chunks) << 2;
        int grow = n0 + row;
        ushort4 v = ushort4{0, 0, 0, 0};
        if (grow < Nn && c4 < K) {
            if (xf32) {
                const float* xr = (const float*)X + (size_t)grow * xstride + c4;
                float4 fv = *(const float4*)xr;
                v = ushort4{f2us(fv.x), f2us(fv.y), f2us(fv.z), f2us(fv.w)};
            } else {
                v = *(const ushort4*)((const bf16*)X + (size_t)grow * xstride + c4);
            }
        }
        *(ushort4*)&Xs[row][c4] = v;
    }
    __syncthreads();

    const int ct0 = w * 7;
    const int ctn = w ? (CTN - 7) : 7;
    f32x4 acc[2][7];
#pragma unroll
    for (int mt = 0; mt < 2; mt++)
#pragma unroll
        for (int ctl = 0; ctl < 7; ctl++)
            acc[mt][ctl] = f32x4{0.f, 0.f, 0.f, 0.f};

    for (int kt = 0; kt < KT; kt++) {
        short8v a0 = *(const short8v*)&Xs[c0][kt * 32 + qd * 8];
        short8v a1 = *(const short8v*)&Xs[16 + c0][kt * 32 + qd * 8];
        const short* wp = WBp + ((size_t)kt * CTN + ct0) * 512 + lane * 8;
#pragma unroll
        for (int ctl = 0; ctl < 7; ctl++) {
            if (ctl < ctn) {
                short8v b = *(const short8v*)(wp + (size_t)ctl * 512);
                acc[0][ctl] = MFMA16(a0, b, acc[0][ctl]);
                acc[1][ctl] = MFMA16(a1, b, acc[1][ctl]);
            }
        }
    }

#pragma unroll
    for (int mt = 0; mt < 2; mt++)
#pragma unroll
        for (int ctl = 0; ctl < 7; ctl++) {
            if (ctl < ctn) {
#pragma unroll
                for (int r = 0; r < 4; r++) {
                    int row = n0 + mt * 16 + qd * 4 + r;
                    int col = (ct0 + ctl) * 16 + c0;
                    if (row < Nn) {
                        if (col < HN) {
                            float v = acc[mt][ctl][r] + bp[col];
                            if (relu) v = fmaxf(v, 0.f);
                            out[(size_t)row * ostride + col] = __float2bfloat16(v);
                        } else if (col == HN && scoreOut) {
                            scoreOut[row] = acc[mt][ctl][r] + bp[HN];
                        }
                    }
                }
            }
        }
}

// ---------------- fused MFMA tower-mix + GRU: 3 waves, in-place h update ----------------
__global__ __launch_bounds__(192) void gru_fused_k(
    const bf16* __restrict__ aggb, bf16* __restrict__ h,
    const short* __restrict__ WB, const float* __restrict__ bpack,
    const short* __restrict__ WBmix, const float* __restrict__ bpmix, int Nn)
{
    __shared__ unsigned short Xs[MB][XSTR];   // [m-slot 0..223 | h-slot 224..447]
    __shared__ float zbuf[MB][CTN * 16];
    const int tid = threadIdx.x;
    const int g = tid >> 6, lane = tid & 63;
    const int qd = lane >> 4, c0 = lane & 15;
    const int n0 = blockIdx.x * MB;

    // stage agg -> m-slot, h -> h-slot (zero pads)
    for (int i = tid; i < MB * (XSTR / 4); i += 192) {
        int row = i / (XSTR / 4);
        int c4 = (i - row * (XSTR / 4)) * 4;
        ushort4 v = ushort4{0, 0, 0, 0};
        if (c4 < HN)
            v = *(const ushort4*)&aggb[(size_t)(n0 + row) * HN + c4];
        else if (c4 >= 224 && c4 < 224 + HN)
            v = *(const ushort4*)&h[(size_t)(n0 + row) * HN + (c4 - 224)];
        *(ushort4*)&Xs[row][c4] = v;
    }
    __syncthreads();

    f32x4 acc[2][CTN];

    // ---- phase 0: m = relu(agg @ W_eff + b_mix), ct split 5/4/4 across waves ----
    const int mct0 = (g == 0) ? 0 : (g == 1) ? 5 : 9;
    const int mctn = (g == 0) ? 5 : 4;
#pragma unroll
    for (int mt = 0; mt < 2; mt++)
#pragma unroll
        for (int ctl = 0; ctl < 5; ctl++)
            acc[mt][ctl] = f32x4{0.f, 0.f, 0.f, 0.f};
    for (int kt = 0; kt < 7; kt++) {
        short8v a0 = *(const short8v*)&Xs[c0][kt * 32 + qd * 8];
        short8v a1 = *(const short8v*)&Xs[16 + c0][kt * 32 + qd * 8];
        const short* wp = WBmix + ((size_t)kt * CTN + mct0) * 512 + lane * 8;
#pragma unroll
        for (int ctl = 0; ctl < 5; ctl++) {
            if (ctl < mctn) {
                short8v b = *(const short8v*)(wp + (size_t)ctl * 512);
                acc[0][ctl] = MFMA16(a0, b, acc[0][ctl]);
                acc[1][ctl] = MFMA16(a1, b, acc[1][ctl]);
            }
        }
    }
#pragma unroll
    for (int mt = 0; mt < 2; mt++)
#pragma unroll
        for (int ctl = 0; ctl < 5; ctl++) {
            if (ctl < mctn) {
#pragma unroll
                for (int r = 0; r < 4; r++) {
                    int row = mt * 16 + qd * 4 + r;
                    int col = (mct0 + ctl) * 16 + c0;
                    zbuf[row][col] = fmaxf(acc[mt][ctl][r] + bpmix[col], 0.f);
                }
            }
        }
    __syncthreads();
    // write m (cols 0..199) into m-slot as bf16; pads stay 0
    for (int i = tid; i < MB * 50; i += 192) {
        int row = i / 50, c4 = (i - row * 50) * 4;
        float4 v = *(const float4*)&zbuf[row][c4];
        *(ushort4*)&Xs[row][c4] = ushort4{f2us(v.x), f2us(v.y), f2us(v.z), f2us(v.w)};
    }
    __syncthreads();

    // ---- phase 1: z,r over full K=448 ; h~ over m-part ----
#pragma unroll
    for (int mt = 0; mt < 2; mt++)
#pragma unroll
        for (int ct = 0; ct < CTN; ct++)
            acc[mt][ct] = f32x4{0.f, 0.f, 0.f, 0.f};

    const int ktEnd = (g == 2) ? 7 : KTN;
    for (int kt = 0; kt < ktEnd; kt++) {
        short8v a0 = *(const short8v*)&Xs[c0][kt * 32 + qd * 8];
        short8v a1 = *(const short8v*)&Xs[16 + c0][kt * 32 + qd * 8];
        const short* wp = WB + (size_t)(g * KTN + kt) * CTN * 512 + lane * 8;
#pragma unroll
        for (int ct = 0; ct < CTN; ct++) {
            short8v b = *(const short8v*)(wp + (size_t)ct * 512);
            acc[0][ct] = MFMA16(a0, b, acc[0][ct]);
            acc[1][ct] = MFMA16(a1, b, acc[1][ct]);
        }
    }
    __syncthreads();

    if (g == 0) {          // z -> zbuf
#pragma unroll
        for (int mt = 0; mt < 2; mt++)
#pragma unroll
            for (int ct = 0; ct < CTN; ct++)
#pragma unroll
                for (int r = 0; r < 4; r++) {
                    int row = mt * 16 + qd * 4 + r;
                    int col = ct * 16 + c0;
                    zbuf[row][col] = sigmf(acc[mt][ct][r] + bpack[col]);
                }
    } else if (g == 1) {   // r -> h-slot := bf16(r*h)
#pragma unroll
        for (int mt = 0; mt < 2; mt++)
#pragma unroll
            for (int ct = 0; ct < CTN; ct++)
#pragma unroll
                for (int r = 0; r < 4; r++) {
                    int row = mt * 16 + qd * 4 + r;
                    int col = ct * 16 + c0;
                    float rr = sigmf(acc[mt][ct][r] + bpack[208 + col]);
                    float hv = us2f(Xs[row][224 + col]);
                    Xs[row][224 + col] = f2us(rr * hv);
                }
    }
    __syncthreads();

    if (g == 2) {
        for (int kt = 7; kt < KTN; kt++) {
            short8v a0 = *(const short8v*)&Xs[c0][kt * 32 + qd * 8];
            short8v a1 = *(const short8v*)&Xs[16 + c0][kt * 32 + qd * 8];
            const short* wp = WB + (size_t)(2 * KTN + kt) * CTN * 512 + lane * 8;
#pragma unroll
            for (int ct = 0; ct < CTN; ct++) {
                short8v b = *(const short8v*)(wp + (size_t)ct * 512);
                acc[0][ct] = MFMA16(a0, b, acc[0][ct]);
                acc[1][ct] = MFMA16(a1, b, acc[1][ct]);
            }
        }
#pragma unroll
        for (int mt = 0; mt < 2; mt++)
#pragma unroll
            for (int ct = 0; ct < CTN; ct++)
#pragma unroll
                for (int r = 0; r < 4; r++) {
                    int row = mt * 16 + qd * 4 + r;
                    int col = ct * 16 + c0;
                    if (col < HN) {
                        float ah = acc[mt][ct][r] + bpack[416 + col];
                        ah = fminf(fmaxf(ah, -15.f), 15.f);
                        float e = __expf(2.f * ah);
                        float htl = (e - 1.f) / (e + 1.f);
                        size_t idx = (size_t)(n0 + row) * HN + col;
                        float hv = b2f(h[idx]);
                        h[idx] = __float2bfloat16(fmaf(zbuf[row][col], htl - hv, hv));
                    }
                }
    }
}

// ---------------- segment max ----------------
__global__ __launch_bounds__(256) void gmax_k(
    const float* __restrict__ score, const int* __restrict__ bv,
    unsigned* __restrict__ gmax_u, int Nn)
{
    __shared__ unsigned lm[GG];
    const int tid = threadIdx.x;
    for (int i = tid; i < GG; i += 256) lm[i] = 0u;
    __syncthreads();
    int n = blockIdx.x * 256 + tid;
    if (n < Nn) atomicMax(&lm[bv[n]], ordkey(score[n]));
    __syncthreads();
    for (int i = tid; i < GG; i += 256)
        if (lm[i]) atomicMax(&gmax_u[i], lm[i]);
}

// ---------------- exp + segment sum ----------------
__global__ __launch_bounds__(256) void exsum_k(
    const float* __restrict__ score, const int* __restrict__ bv,
    const unsigned* __restrict__ gmax_u, float* __restrict__ ex,
    float* __restrict__ gsum, int Nn)
{
    __shared__ float ls[GG];
    const int tid = threadIdx.x;
    for (int i = tid; i < GG; i += 256) ls[i] = 0.f;
    __syncthreads();
    int n = blockIdx.x * 256 + tid;
    if (n < Nn) {
        int g = bv[n];
        float e = __expf(score[n] - ordinv(gmax_u[g]));
        ex[n] = e;
        atomicAdd(&ls[g], e);
    }
    __syncthreads();
    for (int i = tid; i < GG; i += 256)
        if (ls[i] != 0.f) atomicAdd(&gsum[i], ls[i]);
}

// ---------------- weighted readout scatter ----------------
__global__ __launch_bounds__(256) void scatter_k(
    const bf16* __restrict__ feat, const float* __restrict__ ex,
    const float* __restrict__ gsum, const int* __restrict__ bv,
    float* __restrict__ gout, int Nn)
{
    const int tid = threadIdx.x;
    if (tid >= HN) return;
    int n0 = blockIdx.x * NRB;
    int lim = Nn - n0; if (lim > NRB) lim = NRB;
    float acc = 0.f;
    int cur = -1;
    float inv = 0.f;
    for (int i = 0; i < lim; i++) {
        int n = n0 + i;
        int g = bv[n];
        if (g != cur) {
            if (cur >= 0) atomicAdd(&gout[cur * HN + tid], acc);
            acc = 0.f;
            cur = g;
            inv = 1.0f / gsum[g];
        }
        acc = fmaf(ex[n] * inv, b2f(feat[(size_t)n * HN + tid]), acc);
    }
    if (cur >= 0) atomicAdd(&gout[cur * HN + tid], acc);
}

// ---------------- readout MLP ----------------
template <typename T, int OUTF32>
__device__ __forceinline__ void final_impl(
    float* r1s, const float* gout,
    const void* Wr1, const void* br1, const void* Wout, const void* bout,
    void* out, int g, int tid)
{
    if (tid < HN) {
        float v = LDR<T>::get(br1, tid);
        for (int k = 0; k < HN; k++) v = fmaf(gout[g * HN + k], LDR<T>::get(Wr1, (size_t)k * HN + tid), v);
        r1s[tid] = (v == v) ? fmaxf(v, 0.f) : v;
    }
    __syncthreads();
    if (tid < 64) {
        float a = 0.f;
        for (int k = tid; k < HN; k += 64) a = fmaf(r1s[k], LDR<T>::get(Wout, k), a);
        for (int off = 32; off; off >>= 1) a += __shfl_down(a, off, 64);
        if (tid == 0) {
            float res = a + LDR<T>::get(bout, 0);
            if (OUTF32) ((float*)out)[g] = res;
            else        ((bf16*)out)[g] = __float2bfloat16(res);
        }
    }
}

__global__ __launch_bounds__(256) void final_k(
    const int* flag, const float* gout,
    const void* Wr1, const void* br1, const void* Wout, const void* bout, void* out)
{
    __shared__ float r1s[HN];
    const int g = blockIdx.x, tid = threadIdx.x;
    if (*flag) final_impl<float, 1>(r1s, gout, Wr1, br1, Wout, bout, out, g, tid);
    else       final_impl<bf16,  0>(r1s, gout, Wr1, br1, Wout, bout, out, g, tid);
}

extern "C" void kernel_launch(void* const* d_in, const int* in_sizes, int n_in,
                              void* d_out, int out_size, void* d_ws, size_t ws_size,
                              hipStream_t stream)
{
    const void* nf      = d_in[0];
    const void* ef      = d_in[1];
    const int*  ei      = (const int*)d_in[2];
    const int*  bv      = (const int*)d_in[3];
    const void* W_in    = d_in[4];
    const void* b_in    = d_in[5];
    const void* W_edge  = d_in[6];
    const void* b_edge  = d_in[7];
    const void* W_tower = d_in[8];
    const void* W_mix   = d_in[9];
    const void* b_mix   = d_in[10];
    const void* Wz      = d_in[11];
    const void* Uz      = d_in[12];
    const void* bz      = d_in[13];
    const void* Wr      = d_in[14];
    const void* Ur      = d_in[15];
    const void* br      = d_in[16];
    const void* Wh      = d_in[17];
    const void* Uh      = d_in[18];
    const void* bh      = d_in[19];
    const void* W_score = d_in[20];
    const void* b_score = d_in[21];
    const void* W_feat  = d_in[22];
    const void* b_feat  = d_in[23];
    const void* W_r1    = d_in[24];
    const void* b_r1    = d_in[25];
    const void* W_out   = d_in[26];
    const void* b_out   = d_in[27];

    const int* src = ei;
    const int* dst = ei + EE;

    // ---- workspace layout (~115 MB) ----
    const size_t NH = (size_t)NN * HN;
    char* p = (char*)d_ws;
    auto take = [&](size_t bytes) { char* r = p; p += (bytes + 15) & ~(size_t)15; return r; };
    bf16*  h      = (bf16*)take(NH * 2);
    bf16*  aggb   = (bf16*)take(NH * 2);        // bf16 agg; m computed in-kernel; feat reuses
    float* score  = (float*)take(NN * 4);
    float* ex     = (float*)take(NN * 4);
    unsigned* gmax_u = (unsigned*)take((GG + GG + GG * HN) * 4);
    float* gsum   = (float*)(gmax_u + GG);
    float* gout   = gsum + GG;
    short* WB     = (short*)take(WBSZ * 2);
    float* bpack  = (float*)take(3 * 208 * 4);
    short* WBmix  = (short*)take(7 * CTN * 512 * 2);
    float* bpmix  = (float*)take(208 * 4);
    short* WBfs   = (short*)take(7 * CTN * 512 * 2);
    float* bpfs   = (float*)take(208 * 4);
    short* WBin   = (short*)take(4 * CTN * 512 * 2);
    float* bpin   = (float*)take(208 * 4);
    float* Wef    = (float*)take(FE_ * HN * 4);
    float* bef    = (float*)take(HN * 4);
    int*   cnt    = (int*)take(NN * 4);
    int*   off    = (int*)take((NN + 1) * 4);
    int*   cursor = (int*)take(NN * 4);
    int*   part   = (int*)take(512 * 4);
    int*   srcp   = (int*)take(EE * 4);
    int*   eidx   = (int*)take(EE * 4);
    bf16*  efp    = (bf16*)take((size_t)EE * FE_ * 2);
    int*   flag   = (int*)take(16);

    const dim3 blk(256);
    const int zsmall_n4 = (GG + GG + GG * HN) / 4;

    probe_k<<<dim3(1), blk, 0, stream>>>(nf, W_in, flag);

    pack_all_k<<<dim3((PA_TOT + 255) / 256), blk, 0, stream>>>(
        flag, Wz, Uz, bz, Wr, Ur, br, Wh, Uh, bh,
        W_tower, W_mix, b_mix, W_feat, b_feat, W_score, b_score,
        W_in, b_in, W_edge, b_edge,
        WB, bpack, WBmix, bpmix, WBfs, bpfs, WBin, bpin, Wef, bef);

    // CSR build + ef permute (once per launch)
    zero_k<<<dim3((NN / 4 + 255) / 256), blk, 0, stream>>>((float4*)cnt, NN / 4);
    hist_k<<<dim3(EE / 256), blk, 0, stream>>>(dst, cnt, EE);
    const int SB = (NN + 255) / 256;
    scan1_k<<<dim3(SB), blk, 0, stream>>>(cnt, off, part, NN);
    scan2_k<<<dim3(1), dim3(512), 0, stream>>>(part, SB);
    scan3_k<<<dim3(SB), blk, 0, stream>>>(part, off, cursor, NN, EE);
    fill_k<<<dim3(EE / 256), blk, 0, stream>>>(src, dst, cursor, srcp, eidx, EE);
    permute_k<<<dim3(EE / 256), blk, 0, stream>>>(flag, ef, eidx, efp, EE);

    // h = relu(nf @ W_in + b_in)
    gemmm_k<<<dim3(NN / 32), dim3(128), 0, stream>>>(
        flag, 2, nf, FN_, FN_, 4, WBin, bpin, 1, h, HN, (float*)nullptr, NN);

    for (int s = 0; s < STEPS_; s++) {
        msg3_k<<<dim3((NN + NPB - 1) / NPB), blk, 0, stream>>>(
            efp, srcp, off, h, Wef, bef, aggb, NN);
        gru_fused_k<<<dim3(NN / MB), dim3(192), 0, stream>>>(
            aggb, h, WB, bpack, WBmix, bpmix, NN);
    }

    // readout: feat GEMM with fused score column
    zero_k<<<dim3((zsmall_n4 + 255) / 256), blk, 0, stream>>>((float4*)gmax_u, zsmall_n4);
    gemmm_k<<<dim3(NN / 32), dim3(128), 0, stream>>>(
        flag, 0, h, HN, HN, 7, WBfs, bpfs, 0, aggb, HN, score, NN);
    gmax_k<<<dim3((NN + 255) / 256), blk, 0, stream>>>(score, bv, gmax_u, NN);
    exsum_k<<<dim3((NN + 255) / 256), blk, 0, stream>>>(score, bv, gmax_u, ex, gsum, NN);
    scatter_k<<<dim3((NN + NRB - 1) / NRB), blk, 0, stream>>>(aggb, ex, gsum, bv, gout, NN);
    final_k<<<dim3(GG), blk, 0, stream>>>(flag, gout, W_r1, b_r1, W_out, b_out, d_out);
}

// Round 7
// 2165.586 us; speedup vs baseline: 3.2407x; 1.2321x over previous
//
#include <hip/hip_runtime.h>
#include <hip/hip_bf16.h>

typedef __hip_bfloat16 bf16;

#define NN  100000   // nodes
#define EE  800000   // edges
#define FN_ 128      // node feature dim
#define FE_ 16       // edge feature dim
#define HN  200      // hidden dim
#define TT  8        // towers
#define DT_ 25       // per-tower dim
#define GG  64       // graphs
#define STEPS_ 3

#define NPB 64       // dst nodes per msg block
#define NRB 512      // nodes per scatter block

// MFMA geometry
#define MB   32      // nodes per gru block (2 row-tiles of 16)
#define XSTR 456     // gru LDS X row stride in shorts
#define ZSTR 212     // zbuf row stride in dwords (208 + 4 pad: 848*qd % 32 = 16 -> 2-way = free; 16B aligned)
#define CTN  13      // col tiles (13*16 = 208 >= 200)
#define KTN  14      // gru k tiles (14*32 = 448 = 224(m) + 224(h))
#define WBSZ (3 * KTN * CTN * 512)   // gru packed weight shorts

// pack_all region sizes
#define PA_A (WBSZ + 3 * 208)
#define PA_B (7 * CTN * 512 + 208)
#define PA_C (7 * CTN * 512 + 208)
#define PA_D (4 * CTN * 512 + 208)
#define PA_E (FE_ * HN + HN)
#define PA_TOT (PA_A + PA_B + PA_C + PA_D + PA_E)

typedef __attribute__((ext_vector_type(8))) short short8v;
typedef __attribute__((ext_vector_type(4))) float f32x4;
#define MFMA16(a, b, c) __builtin_amdgcn_mfma_f32_16x16x32_bf16(a, b, c, 0, 0, 0)

__device__ __forceinline__ float b2f(bf16 v) { return __bfloat162float(v); }
__device__ __forceinline__ float us2f(unsigned short u) { return __uint_as_float((unsigned)u << 16); }
__device__ __forceinline__ unsigned short f2us(float x) { bf16 t = __float2bfloat16(x); return *(unsigned short*)&t; }
__device__ __forceinline__ float sigmf(float x) { return 1.0f / (1.0f + __expf(-x)); }

template <typename T> struct LDR;
template <> struct LDR<bf16> {
    static __device__ __forceinline__ float get(const void* p, size_t i) {
        return __bfloat162float(((const bf16*)p)[i]);
    }
};
template <> struct LDR<float> {
    static __device__ __forceinline__ float get(const void* p, size_t i) {
        return ((const float*)p)[i];
    }
};
__device__ __forceinline__ float ldsel(const void* p, size_t i, int f) {
    return f ? LDR<float>::get(p, i) : LDR<bf16>::get(p, i);
}

__device__ __forceinline__ unsigned ordkey(float x) {
    unsigned b = __float_as_uint(x);
    return b ^ (unsigned)(((int)b >> 31) | (int)0x80000000);
}
__device__ __forceinline__ float ordinv(unsigned u) {
    unsigned b = (u & 0x80000000u) ? (u ^ 0x80000000u) : ~u;
    return __uint_as_float(b);
}

// ---------------- dtype probe ----------------
__global__ __launch_bounds__(256) void probe_k(const void* nf, const void* Win, int* flag) {
    __shared__ int cnt;
    if (threadIdx.x == 0) cnt = 0;
    __syncthreads();
    const unsigned short* a = (const unsigned short*)nf;
    const unsigned short* b = (const unsigned short*)Win;
    int c = 0;
    for (int i = threadIdx.x; i < 2048; i += 256) {
        float x = us2f(a[i]);
        float y = us2f(b[i]);
        if (!(fabsf(x) < 1e3f)) c++;
        if (!(fabsf(y) < 1e3f)) c++;
    }
    atomicAdd(&cnt, c);
    __syncthreads();
    if (threadIdx.x == 0) flag[0] = (cnt >= 8) ? 1 : 0;
}

// ---------------- zero fill ----------------
__global__ __launch_bounds__(256) void zero_k(float4* __restrict__ p, int n4) {
    int i = blockIdx.x * 256 + threadIdx.x;
    if (i < n4) p[i] = float4{0.f, 0.f, 0.f, 0.f};
}

// ---------------- ALL weight packs in one kernel ----------------
__global__ __launch_bounds__(256) void pack_all_k(
    const int* flag,
    const void* Wz, const void* Uz, const void* bz,
    const void* Wr, const void* Ur, const void* br,
    const void* Wh, const void* Uh, const void* bh,
    const void* Wt, const void* Wmix, const void* bmix,
    const void* Wfeat, const void* bfeat, const void* Wscore, const void* bscore,
    const void* Win, const void* bin,
    const void* Wedge, const void* bedge,
    short* __restrict__ WB, float* __restrict__ bpack,
    short* __restrict__ WBmix, float* __restrict__ bpmix,
    short* __restrict__ WBfs, float* __restrict__ bpfs,
    short* __restrict__ WBin, float* __restrict__ bpin,
    float* __restrict__ Wef, float* __restrict__ bef)
{
    int i = blockIdx.x * 256 + threadIdx.x;
    const int f = *flag;

    if (i < PA_A) {                       // ---- region A: GRU gates [W;U] K=448
        if (i < WBSZ) {
            int j8 = i & 7;
            int e = i >> 3;
            int lane = e & 63; e >>= 6;
            int ct = e % 13; e /= 13;
            int kt = e % 14;
            int g = e / 14;
            int kl = kt * 32 + (lane >> 4) * 8 + j8;
            int col = ct * 16 + (lane & 15);
            int ksrc = (kl < 224) ? kl : kl - 224;
            const void* W = (kl < 224) ? (g == 0 ? Wz : g == 1 ? Wr : Wh)
                                       : (g == 0 ? Uz : g == 1 ? Ur : Uh);
            float v = 0.f;
            if (ksrc < HN && col < HN) v = ldsel(W, (size_t)ksrc * HN + col, f);
            WB[i] = (short)f2us(v);
        } else {
            int t = i - WBSZ;
            int g = t / 208, col = t % 208;
            const void* B = g == 0 ? bz : g == 1 ? br : bh;
            bpack[t] = (col < HN) ? ldsel(B, col, f) : 0.f;
        }
        return;
    }
    i -= PA_A;
    if (i < PA_B) {                       // ---- region B: W_eff = blockdiag(W_tower)@W_mix
        const int tot = 7 * CTN * 512;
        if (i < tot) {
            int j8 = i & 7;
            int e = i >> 3;
            int lane = e & 63; e >>= 6;
            int ct = e % CTN;
            int kt = e / CTN;
            int kl = kt * 32 + (lane >> 4) * 8 + j8;
            int col = ct * 16 + (lane & 15);
            float v = 0.f;
            if (kl < HN && col < HN) {
                int t = kl / DT_, d = kl - t * DT_;
                for (int ee = 0; ee < DT_; ee++) {
                    float wt = ldsel(Wt, (size_t)(t * DT_ + d) * DT_ + ee, f);
                    float wm = ldsel(Wmix, (size_t)(t * DT_ + ee) * HN + col, f);
                    v = fmaf(wt, wm, v);
                }
            }
            WBmix[i] = (short)f2us(v);
        } else {
            int t = i - tot;
            bpmix[t] = (t < HN) ? ldsel(bmix, t, f) : 0.f;
        }
        return;
    }
    i -= PA_B;
    if (i < PA_C) {                       // ---- region C: W_feat with W_score as col 200
        const int tot = 7 * CTN * 512;
        if (i < tot) {
            int j8 = i & 7;
            int e = i >> 3;
            int lane = e & 63; e >>= 6;
            int ct = e % CTN;
            int kt = e / CTN;
            int kl = kt * 32 + (lane >> 4) * 8 + j8;
            int col = ct * 16 + (lane & 15);
            float v = 0.f;
            if (kl < HN) {
                if (col < HN) v = ldsel(Wfeat, (size_t)kl * HN + col, f);
                else if (col == HN) v = ldsel(Wscore, kl, f);
            }
            WBfs[i] = (short)f2us(v);
        } else {
            int t = i - tot;
            float v = 0.f;
            if (t < HN) v = ldsel(bfeat, t, f);
            else if (t == HN) v = ldsel(bscore, 0, f);
            bpfs[t] = v;
        }
        return;
    }
    i -= PA_C;
    if (i < PA_D) {                       // ---- region D: W_in (K=128)
        const int tot = 4 * CTN * 512;
        if (i < tot) {
            int j8 = i & 7;
            int e = i >> 3;
            int lane = e & 63; e >>= 6;
            int ct = e % CTN;
            int kt = e / CTN;
            int kl = kt * 32 + (lane >> 4) * 8 + j8;
            int col = ct * 16 + (lane & 15);
            float v = 0.f;
            if (kl < FN_ && col < HN) v = ldsel(Win, (size_t)kl * HN + col, f);
            WBin[i] = (short)f2us(v);
        } else {
            int t = i - tot;
            bpin[t] = (t < HN) ? ldsel(bin, t, f) : 0.f;
        }
        return;
    }
    i -= PA_D;
    if (i < PA_E) {                       // ---- region E: W_edge as f32 + b_edge
        if (i < FE_ * HN) Wef[i] = ldsel(Wedge, i, f);
        else bef[i - FE_ * HN] = ldsel(bedge, i - FE_ * HN, f);
    }
}

// ---------------- CSR build ----------------
__global__ __launch_bounds__(256) void hist_k(const int* dst, int* cnt, int Ecnt) {
    int e = blockIdx.x * 256 + threadIdx.x;
    if (e < Ecnt) atomicAdd(&cnt[dst[e]], 1);
}

__global__ __launch_bounds__(256) void scan1_k(const int* cnt, int* off, int* part, int Nn) {
    __shared__ int s[256];
    int t = threadIdx.x, i = blockIdx.x * 256 + t;
    int v = (i < Nn) ? cnt[i] : 0;
    s[t] = v; __syncthreads();
    for (int d = 1; d < 256; d <<= 1) {
        int x = (t >= d) ? s[t - d] : 0;
        __syncthreads();
        s[t] += x;
        __syncthreads();
    }
    if (i < Nn) off[i] = s[t] - v;
    if (t == 255) part[blockIdx.x] = s[255];
}

__global__ __launch_bounds__(512) void scan2_k(int* part, int P) {
    __shared__ int s[512];
    int t = threadIdx.x;
    int v = (t < P) ? part[t] : 0;
    s[t] = v; __syncthreads();
    for (int d = 1; d < 512; d <<= 1) {
        int x = (t >= d) ? s[t - d] : 0;
        __syncthreads();
        s[t] += x;
        __syncthreads();
    }
    if (t < P) part[t] = s[t] - v;
}

__global__ __launch_bounds__(256) void scan3_k(const int* part, int* off, int* cursor, int Nn, int Etot) {
    int i = blockIdx.x * 256 + threadIdx.x;
    if (i < Nn) {
        int o = off[i] + part[i >> 8];
        off[i] = o;
        cursor[i] = o;
    }
    if (i == 0) off[Nn] = Etot;
}

__global__ __launch_bounds__(256) void fill_k(
    const int* src, const int* dst, int* cursor, int* srcp, int* eidx, int Ecnt)
{
    int e = blockIdx.x * 256 + threadIdx.x;
    if (e < Ecnt) {
        int p = atomicAdd(&cursor[dst[e]], 1);
        srcp[p] = src[e];
        eidx[p] = e;
    }
}

// ---------------- permute ef rows into CSR order as bf16 ----------------
__global__ __launch_bounds__(256) void permute_k(
    const int* flag, const void* ef, const int* __restrict__ eidx,
    bf16* __restrict__ efp, int Ecnt)
{
    int i = blockIdx.x * 256 + threadIdx.x;
    if (i >= Ecnt) return;
    int e = eidx[i];
    unsigned short row[16];
    if (*flag) {
        const float* er = (const float*)ef + (size_t)e * FE_;
#pragma unroll
        for (int k = 0; k < FE_; k++) row[k] = f2us(er[k]);
    } else {
        const unsigned short* er = (const unsigned short*)ef + (size_t)e * FE_;
#pragma unroll
        for (int k = 0; k < FE_; k++) row[k] = er[k];
    }
    ushort4* o = (ushort4*)(efp + (size_t)i * FE_);
#pragma unroll
    for (int q = 0; q < 4; q++)
        o[q] = ushort4{row[4 * q], row[4 * q + 1], row[4 * q + 2], row[4 * q + 3]};
}

// ---------------- CSR message pass v3: streamed efp, 4-edge unroll ----------------
__global__ __launch_bounds__(256) void msg3_k(
    const bf16* __restrict__ efp, const int* __restrict__ srcp,
    const int* __restrict__ off, const bf16* __restrict__ h,
    const float* __restrict__ Wef, const float* __restrict__ bef,
    bf16* __restrict__ aggb, int Nn)
{
    const int tid = threadIdx.x;
    if (tid >= HN) return;
    const int n0 = blockIdx.x * NPB;
    float wcol[FE_];
#pragma unroll
    for (int k = 0; k < FE_; k++) wcol[k] = Wef[k * HN + tid];
    const float bj = bef[tid];

    for (int dd = 0; dd < NPB; dd++) {
        int d = n0 + dd;
        if (d >= Nn) break;
        int i0 = off[d], i1 = off[d + 1];
        float a = 0.f;
        int i = i0;
        for (; i + 4 <= i1; i += 4) {
            int s0 = srcp[i], s1 = srcp[i + 1], s2 = srcp[i + 2], s3 = srcp[i + 3];
            const short8v* fr = (const short8v*)(efp + (size_t)i * FE_);
            short8v fa0 = fr[0], fb0 = fr[1], fa1 = fr[2], fb1 = fr[3];
            short8v fa2 = fr[4], fb2 = fr[5], fa3 = fr[6], fb3 = fr[7];
            unsigned short h0 = *(const unsigned short*)&h[(size_t)s0 * HN + tid];
            unsigned short h1 = *(const unsigned short*)&h[(size_t)s1 * HN + tid];
            unsigned short h2 = *(const unsigned short*)&h[(size_t)s2 * HN + tid];
            unsigned short h3 = *(const unsigned short*)&h[(size_t)s3 * HN + tid];
            float g0 = bj, g1 = bj, g2 = bj, g3 = bj;
#pragma unroll
            for (int k = 0; k < 8; k++) {
                g0 = fmaf(us2f((unsigned short)fa0[k]), wcol[k], g0);
                g1 = fmaf(us2f((unsigned short)fa1[k]), wcol[k], g1);
                g2 = fmaf(us2f((unsigned short)fa2[k]), wcol[k], g2);
                g3 = fmaf(us2f((unsigned short)fa3[k]), wcol[k], g3);
            }
#pragma unroll
            for (int k = 0; k < 8; k++) {
                g0 = fmaf(us2f((unsigned short)fb0[k]), wcol[8 + k], g0);
                g1 = fmaf(us2f((unsigned short)fb1[k]), wcol[8 + k], g1);
                g2 = fmaf(us2f((unsigned short)fb2[k]), wcol[8 + k], g2);
                g3 = fmaf(us2f((unsigned short)fb3[k]), wcol[8 + k], g3);
            }
            a = fmaf(sigmf(g0), us2f(h0), a);
            a = fmaf(sigmf(g1), us2f(h1), a);
            a = fmaf(sigmf(g2), us2f(h2), a);
            a = fmaf(sigmf(g3), us2f(h3), a);
        }
        for (; i < i1; i++) {
            int s = srcp[i];
            const short8v* fr = (const short8v*)(efp + (size_t)i * FE_);
            short8v fa = fr[0], fb = fr[1];
            float g = bj;
#pragma unroll
            for (int k = 0; k < 8; k++) g = fmaf(us2f((unsigned short)fa[k]), wcol[k], g);
#pragma unroll
            for (int k = 0; k < 8; k++) g = fmaf(us2f((unsigned short)fb[k]), wcol[8 + k], g);
            a = fmaf(sigmf(g), b2f(h[(size_t)s * HN + tid]), a);
        }
        aggb[(size_t)d * HN + tid] = __float2bfloat16(a);
    }
}

// ---------------- generic MFMA GEMM (+optional fused score col 200) ----------------
__global__ __launch_bounds__(128) void gemmm_k(
    const int* flag, int xmode, const void* X, int K, int xstride, int KT,
    const short* __restrict__ WBp, const float* __restrict__ bp, int relu,
    bf16* __restrict__ out, int ostride, float* __restrict__ scoreOut, int Nn)
{
    __shared__ unsigned short Xs[32][232];
    const int tid = threadIdx.x;
    const int w = tid >> 6, lane = tid & 63;
    const int qd = lane >> 4, c0 = lane & 15;
    const int n0 = blockIdx.x * 32;
    const int xf32 = (xmode == 2) ? *flag : xmode;
    const int chunks = (KT * 32) >> 2;

    for (int i = tid; i < 32 * chunks; i += 128) {
        int row = i / chunks, c4 = (i - row * chunks) << 2;
        int grow = n0 + row;
        ushort4 v = ushort4{0, 0, 0, 0};
        if (grow < Nn && c4 < K) {
            if (xf32) {
                const float* xr = (const float*)X + (size_t)grow * xstride + c4;
                float4 fv = *(const float4*)xr;
                v = ushort4{f2us(fv.x), f2us(fv.y), f2us(fv.z), f2us(fv.w)};
            } else {
                v = *(const ushort4*)((const bf16*)X + (size_t)grow * xstride + c4);
            }
        }
        *(ushort4*)&Xs[row][c4] = v;
    }
    __syncthreads();

    const int ct0 = w * 7;
    const int ctn = w ? (CTN - 7) : 7;
    f32x4 acc[2][7];
#pragma unroll
    for (int mt = 0; mt < 2; mt++)
#pragma unroll
        for (int ctl = 0; ctl < 7; ctl++)
            acc[mt][ctl] = f32x4{0.f, 0.f, 0.f, 0.f};

    for (int kt = 0; kt < KT; kt++) {
        short8v a0 = *(const short8v*)&Xs[c0][kt * 32 + qd * 8];
        short8v a1 = *(const short8v*)&Xs[16 + c0][kt * 32 + qd * 8];
        const short* wp = WBp + ((size_t)kt * CTN + ct0) * 512 + lane * 8;
#pragma unroll
        for (int ctl = 0; ctl < 7; ctl++) {
            if (ctl < ctn) {
                short8v b = *(const short8v*)(wp + (size_t)ctl * 512);
                acc[0][ctl] = MFMA16(a0, b, acc[0][ctl]);
                acc[1][ctl] = MFMA16(a1, b, acc[1][ctl]);
            }
        }
    }

#pragma unroll
    for (int mt = 0; mt < 2; mt++)
#pragma unroll
        for (int ctl = 0; ctl < 7; ctl++) {
            if (ctl < ctn) {
#pragma unroll
                for (int r = 0; r < 4; r++) {
                    int row = n0 + mt * 16 + qd * 4 + r;
                    int col = (ct0 + ctl) * 16 + c0;
                    if (row < Nn) {
                        if (col < HN) {
                            float v = acc[mt][ctl][r] + bp[col];
                            if (relu) v = fmaxf(v, 0.f);
                            out[(size_t)row * ostride + col] = __float2bfloat16(v);
                        } else if (col == HN && scoreOut) {
                            scoreOut[row] = acc[mt][ctl][r] + bp[HN];
                        }
                    }
                }
            }
        }
}

// ---------------- fused MFMA tower-mix + GRU v2: 4 waves, interleaved col-split ----------------
// col tiles: phase0 m-GEMM 13 tiles (c=4j+w); phase1 [z|r|q] 39 tiles (gate = c/13);
// phase2 accumulates (r*h)@Uh into the q tiles each wave kept in registers.
__global__ __launch_bounds__(256, 2) void gru2_k(
    const bf16* __restrict__ aggb, bf16* __restrict__ h,
    const short* __restrict__ WB, const float* __restrict__ bpack,
    const short* __restrict__ WBmix, const float* __restrict__ bpmix, int Nn)
{
    __shared__ unsigned short Xs[MB][XSTR];   // [m-slot 0..223 | h-slot 224..447]
    __shared__ float zbuf[MB][ZSTR];
    const int tid = threadIdx.x;
    const int w = tid >> 6, lane = tid & 63;
    const int qd = lane >> 4, c0 = lane & 15;
    const int n0 = blockIdx.x * MB;

    // stage agg -> m-slot, h -> h-slot (zero pads)
    for (int i = tid; i < MB * (XSTR / 4); i += 256) {
        int row = i / (XSTR / 4);
        int c4 = (i - row * (XSTR / 4)) * 4;
        ushort4 v = ushort4{0, 0, 0, 0};
        if (c4 < HN)
            v = *(const ushort4*)&aggb[(size_t)(n0 + row) * HN + c4];
        else if (c4 >= 224 && c4 < 224 + HN)
            v = *(const ushort4*)&h[(size_t)(n0 + row) * HN + (c4 - 224)];
        *(ushort4*)&Xs[row][c4] = v;
    }
    __syncthreads();

    f32x4 acc[2][10];

    // ---- phase 0: m = relu(agg @ W_eff + b_mix); tiles c = 4j+w < 13 ----
#pragma unroll
    for (int mt = 0; mt < 2; mt++)
#pragma unroll
        for (int j = 0; j < 4; j++) acc[mt][j] = f32x4{0.f, 0.f, 0.f, 0.f};
    for (int kt = 0; kt < 7; kt++) {
        short8v a0 = *(const short8v*)&Xs[c0][kt * 32 + qd * 8];
        short8v a1 = *(const short8v*)&Xs[16 + c0][kt * 32 + qd * 8];
#pragma unroll
        for (int j = 0; j < 4; j++) {
            int c = 4 * j + w;
            if (c < 13) {
                short8v b = *(const short8v*)(WBmix + ((size_t)kt * CTN + c) * 512 + lane * 8);
                acc[0][j] = MFMA16(a0, b, acc[0][j]);
                acc[1][j] = MFMA16(a1, b, acc[1][j]);
            }
        }
    }
#pragma unroll
    for (int j = 0; j < 4; j++) {
        int c = 4 * j + w;
        if (c < 13) {
#pragma unroll
            for (int mt = 0; mt < 2; mt++)
#pragma unroll
                for (int r = 0; r < 4; r++) {
                    int row = mt * 16 + qd * 4 + r;
                    int col = c * 16 + c0;
                    zbuf[row][col] = fmaxf(acc[mt][j][r] + bpmix[col], 0.f);
                }
        }
    }
    __syncthreads();
    // zbuf (m, f32) -> Xs m-slot as bf16; pads 200..223 remain 0
    for (int i = tid; i < MB * 50; i += 256) {
        int row = i / 50, c4 = (i - row * 50) * 4;
        float4 v = *(const float4*)&zbuf[row][c4];
        *(ushort4*)&Xs[row][c4] = ushort4{f2us(v.x), f2us(v.y), f2us(v.z), f2us(v.w)};
    }
    __syncthreads();

    // ---- phase 1: [z|r|q] = [m|h] @ [[Wz|Wr|Wh],[Uz|Ur|0]]; q tiles use kt<7 only ----
#pragma unroll
    for (int mt = 0; mt < 2; mt++)
#pragma unroll
        for (int j = 0; j < 10; j++) acc[mt][j] = f32x4{0.f, 0.f, 0.f, 0.f};
    for (int kt = 0; kt < KTN; kt++) {
        short8v a0 = *(const short8v*)&Xs[c0][kt * 32 + qd * 8];
        short8v a1 = *(const short8v*)&Xs[16 + c0][kt * 32 + qd * 8];
#pragma unroll
        for (int j = 0; j < 10; j++) {
            int c = 4 * j + w;
            if (c < 39) {
                int g = c / 13, ctl = c - g * 13;
                if (g < 2 || kt < 7) {
                    short8v b = *(const short8v*)(WB + ((size_t)(g * KTN + kt) * CTN + ctl) * 512 + lane * 8);
                    acc[0][j] = MFMA16(a0, b, acc[0][j]);
                    acc[1][j] = MFMA16(a1, b, acc[1][j]);
                }
            }
        }
    }
    __syncthreads();   // all phase-1 reads of Xs done

    // elementwise: z -> zbuf ; r -> Xs h-slot := bf16(r*h) ; q stays in regs
#pragma unroll
    for (int j = 0; j < 10; j++) {
        int c = 4 * j + w;
        if (c < 26) {
            int g = c / 13, ctl = c - g * 13;
            if (g == 0) {
#pragma unroll
                for (int mt = 0; mt < 2; mt++)
#pragma unroll
                    for (int r = 0; r < 4; r++) {
                        int row = mt * 16 + qd * 4 + r;
                        int col = ctl * 16 + c0;
                        zbuf[row][col] = sigmf(acc[mt][j][r] + bpack[col]);
                    }
            } else {
#pragma unroll
                for (int mt = 0; mt < 2; mt++)
#pragma unroll
                    for (int r = 0; r < 4; r++) {
                        int row = mt * 16 + qd * 4 + r;
                        int col = ctl * 16 + c0;
                        float rr = sigmf(acc[mt][j][r] + bpack[208 + col]);
                        float hv = us2f(Xs[row][224 + col]);
                        Xs[row][224 + col] = f2us(rr * hv);
                    }
            }
        }
    }
    __syncthreads();   // rh + zbuf visible

    // ---- phase 2: q += (r*h) @ Uh (kt 7..13 of g=2 pack) ----
    for (int kt = 7; kt < KTN; kt++) {
        short8v a0 = *(const short8v*)&Xs[c0][kt * 32 + qd * 8];
        short8v a1 = *(const short8v*)&Xs[16 + c0][kt * 32 + qd * 8];
#pragma unroll
        for (int j = 0; j < 10; j++) {
            int c = 4 * j + w;
            if (c >= 26 && c < 39) {
                int ctl = c - 26;
                short8v b = *(const short8v*)(WB + ((size_t)(2 * KTN + kt) * CTN + ctl) * 512 + lane * 8);
                acc[0][j] = MFMA16(a0, b, acc[0][j]);
                acc[1][j] = MFMA16(a1, b, acc[1][j]);
            }
        }
    }

    // epilogue: h = h + z*(tanh(q + bh) - h)
#pragma unroll
    for (int j = 0; j < 10; j++) {
        int c = 4 * j + w;
        if (c >= 26 && c < 39) {
            int ctl = c - 26;
#pragma unroll
            for (int mt = 0; mt < 2; mt++)
#pragma unroll
                for (int r = 0; r < 4; r++) {
                    int row = mt * 16 + qd * 4 + r;
                    int col = ctl * 16 + c0;
                    if (col < HN) {
                        float ah = acc[mt][j][r] + bpack[416 + col];
                        ah = fminf(fmaxf(ah, -15.f), 15.f);
                        float e = __expf(2.f * ah);
                        float htl = (e - 1.f) / (e + 1.f);
                        size_t idx = (size_t)(n0 + row) * HN + col;
                        float hv = b2f(h[idx]);
                        h[idx] = __float2bfloat16(fmaf(zbuf[row][col], htl - hv, hv));
                    }
                }
        }
    }
}

// ---------------- segment max ----------------
__global__ __launch_bounds__(256) void gmax_k(
    const float* __restrict__ score, const int* __restrict__ bv,
    unsigned* __restrict__ gmax_u, int Nn)
{
    __shared__ unsigned lm[GG];
    const int tid = threadIdx.x;
    for (int i = tid; i < GG; i += 256) lm[i] = 0u;
    __syncthreads();
    int n = blockIdx.x * 256 + tid;
    if (n < Nn) atomicMax(&lm[bv[n]], ordkey(score[n]));
    __syncthreads();
    for (int i = tid; i < GG; i += 256)
        if (lm[i]) atomicMax(&gmax_u[i], lm[i]);
}

// ---------------- exp + segment sum ----------------
__global__ __launch_bounds__(256) void exsum_k(
    const float* __restrict__ score, const int* __restrict__ bv,
    const unsigned* __restrict__ gmax_u, float* __restrict__ ex,
    float* __restrict__ gsum, int Nn)
{
    __shared__ float ls[GG];
    const int tid = threadIdx.x;
    for (int i = tid; i < GG; i += 256) ls[i] = 0.f;
    __syncthreads();
    int n = blockIdx.x * 256 + tid;
    if (n < Nn) {
        int g = bv[n];
        float e = __expf(score[n] - ordinv(gmax_u[g]));
        ex[n] = e;
        atomicAdd(&ls[g], e);
    }
    __syncthreads();
    for (int i = tid; i < GG; i += 256)
        if (ls[i] != 0.f) atomicAdd(&gsum[i], ls[i]);
}

// ---------------- weighted readout scatter ----------------
__global__ __launch_bounds__(256) void scatter_k(
    const bf16* __restrict__ feat, const float* __restrict__ ex,
    const float* __restrict__ gsum, const int* __restrict__ bv,
    float* __restrict__ gout, int Nn)
{
    const int tid = threadIdx.x;
    if (tid >= HN) return;
    int n0 = blockIdx.x * NRB;
    int lim = Nn - n0; if (lim > NRB) lim = NRB;
    float acc = 0.f;
    int cur = -1;
    float inv = 0.f;
    for (int i = 0; i < lim; i++) {
        int n = n0 + i;
        int g = bv[n];
        if (g != cur) {
            if (cur >= 0) atomicAdd(&gout[cur * HN + tid], acc);
            acc = 0.f;
            cur = g;
            inv = 1.0f / gsum[g];
        }
        acc = fmaf(ex[n] * inv, b2f(feat[(size_t)n * HN + tid]), acc);
    }
    if (cur >= 0) atomicAdd(&gout[cur * HN + tid], acc);
}

// ---------------- readout MLP ----------------
template <typename T, int OUTF32>
__device__ __forceinline__ void final_impl(
    float* r1s, const float* gout,
    const void* Wr1, const void* br1, const void* Wout, const void* bout,
    void* out, int g, int tid)
{
    if (tid < HN) {
        float v = LDR<T>::get(br1, tid);
        for (int k = 0; k < HN; k++) v = fmaf(gout[g * HN + k], LDR<T>::get(Wr1, (size_t)k * HN + tid), v);
        r1s[tid] = (v == v) ? fmaxf(v, 0.f) : v;
    }
    __syncthreads();
    if (tid < 64) {
        float a = 0.f;
        for (int k = tid; k < HN; k += 64) a = fmaf(r1s[k], LDR<T>::get(Wout, k), a);
        for (int off = 32; off; off >>= 1) a += __shfl_down(a, off, 64);
        if (tid == 0) {
            float res = a + LDR<T>::get(bout, 0);
            if (OUTF32) ((float*)out)[g] = res;
            else        ((bf16*)out)[g] = __float2bfloat16(res);
        }
    }
}

__global__ __launch_bounds__(256) void final_k(
    const int* flag, const float* gout,
    const void* Wr1, const void* br1, const void* Wout, const void* bout, void* out)
{
    __shared__ float r1s[HN];
    const int g = blockIdx.x, tid = threadIdx.x;
    if (*flag) final_impl<float, 1>(r1s, gout, Wr1, br1, Wout, bout, out, g, tid);
    else       final_impl<bf16,  0>(r1s, gout, Wr1, br1, Wout, bout, out, g, tid);
}

extern "C" void kernel_launch(void* const* d_in, const int* in_sizes, int n_in,
                              void* d_out, int out_size, void* d_ws, size_t ws_size,
                              hipStream_t stream)
{
    const void* nf      = d_in[0];
    const void* ef      = d_in[1];
    const int*  ei      = (const int*)d_in[2];
    const int*  bv      = (const int*)d_in[3];
    const void* W_in    = d_in[4];
    const void* b_in    = d_in[5];
    const void* W_edge  = d_in[6];
    const void* b_edge  = d_in[7];
    const void* W_tower = d_in[8];
    const void* W_mix   = d_in[9];
    const void* b_mix   = d_in[10];
    const void* Wz      = d_in[11];
    const void* Uz      = d_in[12];
    const void* bz      = d_in[13];
    const void* Wr      = d_in[14];
    const void* Ur      = d_in[15];
    const void* br      = d_in[16];
    const void* Wh      = d_in[17];
    const void* Uh      = d_in[18];
    const void* bh      = d_in[19];
    const void* W_score = d_in[20];
    const void* b_score = d_in[21];
    const void* W_feat  = d_in[22];
    const void* b_feat  = d_in[23];
    const void* W_r1    = d_in[24];
    const void* b_r1    = d_in[25];
    const void* W_out   = d_in[26];
    const void* b_out   = d_in[27];

    const int* src = ei;
    const int* dst = ei + EE;

    // ---- workspace layout (~115 MB) ----
    const size_t NH = (size_t)NN * HN;
    char* p = (char*)d_ws;
    auto take = [&](size_t bytes) { char* r = p; p += (bytes + 15) & ~(size_t)15; return r; };
    bf16*  h      = (bf16*)take(NH * 2);
    bf16*  aggb   = (bf16*)take(NH * 2);        // bf16 agg; feat reuses
    float* score  = (float*)take(NN * 4);
    float* ex     = (float*)take(NN * 4);
    unsigned* gmax_u = (unsigned*)take((GG + GG + GG * HN) * 4);
    float* gsum   = (float*)(gmax_u + GG);
    float* gout   = gsum + GG;
    short* WB     = (short*)take(WBSZ * 2);
    float* bpack  = (float*)take(3 * 208 * 4);
    short* WBmix  = (short*)take(7 * CTN * 512 * 2);
    float* bpmix  = (float*)take(208 * 4);
    short* WBfs   = (short*)take(7 * CTN * 512 * 2);
    float* bpfs   = (float*)take(208 * 4);
    short* WBin   = (short*)take(4 * CTN * 512 * 2);
    float* bpin   = (float*)take(208 * 4);
    float* Wef    = (float*)take(FE_ * HN * 4);
    float* bef    = (float*)take(HN * 4);
    int*   cnt    = (int*)take(NN * 4);
    int*   off    = (int*)take((NN + 1) * 4);
    int*   cursor = (int*)take(NN * 4);
    int*   part   = (int*)take(512 * 4);
    int*   srcp   = (int*)take(EE * 4);
    int*   eidx   = (int*)take(EE * 4);
    bf16*  efp    = (bf16*)take((size_t)EE * FE_ * 2);
    int*   flag   = (int*)take(16);

    const dim3 blk(256);
    const int zsmall_n4 = (GG + GG + GG * HN) / 4;

    probe_k<<<dim3(1), blk, 0, stream>>>(nf, W_in, flag);

    pack_all_k<<<dim3((PA_TOT + 255) / 256), blk, 0, stream>>>(
        flag, Wz, Uz, bz, Wr, Ur, br, Wh, Uh, bh,
        W_tower, W_mix, b_mix, W_feat, b_feat, W_score, b_score,
        W_in, b_in, W_edge, b_edge,
        WB, bpack, WBmix, bpmix, WBfs, bpfs, WBin, bpin, Wef, bef);

    // CSR build + ef permute (once per launch)
    zero_k<<<dim3((NN / 4 + 255) / 256), blk, 0, stream>>>((float4*)cnt, NN / 4);
    hist_k<<<dim3(EE / 256), blk, 0, stream>>>(dst, cnt, EE);
    const int SB = (NN + 255) / 256;
    scan1_k<<<dim3(SB), blk, 0, stream>>>(cnt, off, part, NN);
    scan2_k<<<dim3(1), dim3(512), 0, stream>>>(part, SB);
    scan3_k<<<dim3(SB), blk, 0, stream>>>(part, off, cursor, NN, EE);
    fill_k<<<dim3(EE / 256), blk, 0, stream>>>(src, dst, cursor, srcp, eidx, EE);
    permute_k<<<dim3(EE / 256), blk, 0, stream>>>(flag, ef, eidx, efp, EE);

    // h = relu(nf @ W_in + b_in)
    gemmm_k<<<dim3(NN / 32), dim3(128), 0, stream>>>(
        flag, 2, nf, FN_, FN_, 4, WBin, bpin, 1, h, HN, (float*)nullptr, NN);

    for (int s = 0; s < STEPS_; s++) {
        msg3_k<<<dim3((NN + NPB - 1) / NPB), blk, 0, stream>>>(
            efp, srcp, off, h, Wef, bef, aggb, NN);
        gru2_k<<<dim3(NN / MB), dim3(256), 0, stream>>>(
            aggb, h, WB, bpack, WBmix, bpmix, NN);
    }

    // readout: feat GEMM with fused score column
    zero_k<<<dim3((zsmall_n4 + 255) / 256), blk, 0, stream>>>((float4*)gmax_u, zsmall_n4);
    gemmm_k<<<dim3(NN / 32), dim3(128), 0, stream>>>(
        flag, 0, h, HN, HN, 7, WBfs, bpfs, 0, aggb, HN, score, NN);
    gmax_k<<<dim3((NN + 255) / 256), blk, 0, stream>>>(score, bv, gmax_u, NN);
    exsum_k<<<dim3((NN + 255) / 256), blk, 0, stream>>>(score, bv, gmax_u, ex, gsum, NN);
    scatter_k<<<dim3((NN + NRB - 1) / NRB), blk, 0, stream>>>(aggb, ex, gsum, bv, gout, NN);
    final_k<<<dim3(GG), blk, 0, stream>>>(flag, gout, W_r1, b_r1, W_out, b_out, d_out);
}

// Round 8
// 2080.913 us; speedup vs baseline: 3.3726x; 1.0407x over previous
//
#include <hip/hip_runtime.h>
#include <hip/hip_bf16.h>

typedef __hip_bfloat16 bf16;

#define NN  100000   // nodes
#define EE  800000   // edges
#define FN_ 128      // node feature dim
#define FE_ 16       // edge feature dim
#define HN  200      // hidden dim
#define TT  8        // towers
#define DT_ 25       // per-tower dim
#define GG  64       // graphs
#define STEPS_ 3

#define NPB 64       // dst nodes per msg block
#define NRB 512      // nodes per scatter block

// MFMA geometry
#define MB3  64      // nodes per gru block (4 row-tiles of 16)
#define XSTR 456     // gru LDS X row stride in shorts (228 dwords ≡ 4 mod 32: even b128 spread)
#define CTN  13      // col tiles (13*16 = 208 >= 200)
#define KTN  14      // gru k tiles (14*32 = 448 = 224(m) + 224(h))
#define WBSZ (3 * KTN * CTN * 512)   // gru packed weight shorts

// pack_all region sizes
#define PA_A (WBSZ + 3 * 208)
#define PA_B (7 * CTN * 512 + 208)
#define PA_C (7 * CTN * 512 + 208)
#define PA_D (4 * CTN * 512 + 208)
#define PA_E (FE_ * HN + HN)
#define PA_TOT (PA_A + PA_B + PA_C + PA_D + PA_E)

typedef __attribute__((ext_vector_type(8))) short short8v;
typedef __attribute__((ext_vector_type(4))) float f32x4;
#define MFMA16(a, b, c) __builtin_amdgcn_mfma_f32_16x16x32_bf16(a, b, c, 0, 0, 0)

__device__ __forceinline__ float b2f(bf16 v) { return __bfloat162float(v); }
__device__ __forceinline__ float us2f(unsigned short u) { return __uint_as_float((unsigned)u << 16); }
__device__ __forceinline__ unsigned short f2us(float x) { bf16 t = __float2bfloat16(x); return *(unsigned short*)&t; }
__device__ __forceinline__ float sigmf(float x) { return 1.0f / (1.0f + __expf(-x)); }

template <typename T> struct LDR;
template <> struct LDR<bf16> {
    static __device__ __forceinline__ float get(const void* p, size_t i) {
        return __bfloat162float(((const bf16*)p)[i]);
    }
};
template <> struct LDR<float> {
    static __device__ __forceinline__ float get(const void* p, size_t i) {
        return ((const float*)p)[i];
    }
};
__device__ __forceinline__ float ldsel(const void* p, size_t i, int f) {
    return f ? LDR<float>::get(p, i) : LDR<bf16>::get(p, i);
}

__device__ __forceinline__ unsigned ordkey(float x) {
    unsigned b = __float_as_uint(x);
    return b ^ (unsigned)(((int)b >> 31) | (int)0x80000000);
}
__device__ __forceinline__ float ordinv(unsigned u) {
    unsigned b = (u & 0x80000000u) ? (u ^ 0x80000000u) : ~u;
    return __uint_as_float(b);
}

// ---------------- dtype probe ----------------
__global__ __launch_bounds__(256) void probe_k(const void* nf, const void* Win, int* flag) {
    __shared__ int cnt;
    if (threadIdx.x == 0) cnt = 0;
    __syncthreads();
    const unsigned short* a = (const unsigned short*)nf;
    const unsigned short* b = (const unsigned short*)Win;
    int c = 0;
    for (int i = threadIdx.x; i < 2048; i += 256) {
        float x = us2f(a[i]);
        float y = us2f(b[i]);
        if (!(fabsf(x) < 1e3f)) c++;
        if (!(fabsf(y) < 1e3f)) c++;
    }
    atomicAdd(&cnt, c);
    __syncthreads();
    if (threadIdx.x == 0) flag[0] = (cnt >= 8) ? 1 : 0;
}

// ---------------- zero fill ----------------
__global__ __launch_bounds__(256) void zero_k(float4* __restrict__ p, int n4) {
    int i = blockIdx.x * 256 + threadIdx.x;
    if (i < n4) p[i] = float4{0.f, 0.f, 0.f, 0.f};
}

// ---------------- ALL weight packs in one kernel ----------------
__global__ __launch_bounds__(256) void pack_all_k(
    const int* flag,
    const void* Wz, const void* Uz, const void* bz,
    const void* Wr, const void* Ur, const void* br,
    const void* Wh, const void* Uh, const void* bh,
    const void* Wt, const void* Wmix, const void* bmix,
    const void* Wfeat, const void* bfeat, const void* Wscore, const void* bscore,
    const void* Win, const void* bin,
    const void* Wedge, const void* bedge,
    short* __restrict__ WB, float* __restrict__ bpack,
    short* __restrict__ WBmix, float* __restrict__ bpmix,
    short* __restrict__ WBfs, float* __restrict__ bpfs,
    short* __restrict__ WBin, float* __restrict__ bpin,
    float* __restrict__ Wef, float* __restrict__ bef)
{
    int i = blockIdx.x * 256 + threadIdx.x;
    const int f = *flag;

    if (i < PA_A) {                       // ---- region A: GRU gates [W;U] K=448
        if (i < WBSZ) {
            int j8 = i & 7;
            int e = i >> 3;
            int lane = e & 63; e >>= 6;
            int ct = e % 13; e /= 13;
            int kt = e % 14;
            int g = e / 14;
            int kl = kt * 32 + (lane >> 4) * 8 + j8;
            int col = ct * 16 + (lane & 15);
            int ksrc = (kl < 224) ? kl : kl - 224;
            const void* W = (kl < 224) ? (g == 0 ? Wz : g == 1 ? Wr : Wh)
                                       : (g == 0 ? Uz : g == 1 ? Ur : Uh);
            float v = 0.f;
            if (ksrc < HN && col < HN) v = ldsel(W, (size_t)ksrc * HN + col, f);
            WB[i] = (short)f2us(v);
        } else {
            int t = i - WBSZ;
            int g = t / 208, col = t % 208;
            const void* B = g == 0 ? bz : g == 1 ? br : bh;
            bpack[t] = (col < HN) ? ldsel(B, col, f) : 0.f;
        }
        return;
    }
    i -= PA_A;
    if (i < PA_B) {                       // ---- region B: W_eff = blockdiag(W_tower)@W_mix
        const int tot = 7 * CTN * 512;
        if (i < tot) {
            int j8 = i & 7;
            int e = i >> 3;
            int lane = e & 63; e >>= 6;
            int ct = e % CTN;
            int kt = e / CTN;
            int kl = kt * 32 + (lane >> 4) * 8 + j8;
            int col = ct * 16 + (lane & 15);
            float v = 0.f;
            if (kl < HN && col < HN) {
                int t = kl / DT_, d = kl - t * DT_;
                for (int ee = 0; ee < DT_; ee++) {
                    float wt = ldsel(Wt, (size_t)(t * DT_ + d) * DT_ + ee, f);
                    float wm = ldsel(Wmix, (size_t)(t * DT_ + ee) * HN + col, f);
                    v = fmaf(wt, wm, v);
                }
            }
            WBmix[i] = (short)f2us(v);
        } else {
            int t = i - tot;
            bpmix[t] = (t < HN) ? ldsel(bmix, t, f) : 0.f;
        }
        return;
    }
    i -= PA_B;
    if (i < PA_C) {                       // ---- region C: W_feat with W_score as col 200
        const int tot = 7 * CTN * 512;
        if (i < tot) {
            int j8 = i & 7;
            int e = i >> 3;
            int lane = e & 63; e >>= 6;
            int ct = e % CTN;
            int kt = e / CTN;
            int kl = kt * 32 + (lane >> 4) * 8 + j8;
            int col = ct * 16 + (lane & 15);
            float v = 0.f;
            if (kl < HN) {
                if (col < HN) v = ldsel(Wfeat, (size_t)kl * HN + col, f);
                else if (col == HN) v = ldsel(Wscore, kl, f);
            }
            WBfs[i] = (short)f2us(v);
        } else {
            int t = i - tot;
            float v = 0.f;
            if (t < HN) v = ldsel(bfeat, t, f);
            else if (t == HN) v = ldsel(bscore, 0, f);
            bpfs[t] = v;
        }
        return;
    }
    i -= PA_C;
    if (i < PA_D) {                       // ---- region D: W_in (K=128)
        const int tot = 4 * CTN * 512;
        if (i < tot) {
            int j8 = i & 7;
            int e = i >> 3;
            int lane = e & 63; e >>= 6;
            int ct = e % CTN;
            int kt = e / CTN;
            int kl = kt * 32 + (lane >> 4) * 8 + j8;
            int col = ct * 16 + (lane & 15);
            float v = 0.f;
            if (kl < FN_ && col < HN) v = ldsel(Win, (size_t)kl * HN + col, f);
            WBin[i] = (short)f2us(v);
        } else {
            int t = i - tot;
            bpin[t] = (t < HN) ? ldsel(bin, t, f) : 0.f;
        }
        return;
    }
    i -= PA_D;
    if (i < PA_E) {                       // ---- region E: W_edge as f32 + b_edge
        if (i < FE_ * HN) Wef[i] = ldsel(Wedge, i, f);
        else bef[i - FE_ * HN] = ldsel(bedge, i - FE_ * HN, f);
    }
}

// ---------------- CSR build ----------------
__global__ __launch_bounds__(256) void hist_k(const int* dst, int* cnt, int Ecnt) {
    int e = blockIdx.x * 256 + threadIdx.x;
    if (e < Ecnt) atomicAdd(&cnt[dst[e]], 1);
}

__global__ __launch_bounds__(256) void scan1_k(const int* cnt, int* off, int* part, int Nn) {
    __shared__ int s[256];
    int t = threadIdx.x, i = blockIdx.x * 256 + t;
    int v = (i < Nn) ? cnt[i] : 0;
    s[t] = v; __syncthreads();
    for (int d = 1; d < 256; d <<= 1) {
        int x = (t >= d) ? s[t - d] : 0;
        __syncthreads();
        s[t] += x;
        __syncthreads();
    }
    if (i < Nn) off[i] = s[t] - v;
    if (t == 255) part[blockIdx.x] = s[255];
}

__global__ __launch_bounds__(512) void scan2_k(int* part, int P) {
    __shared__ int s[512];
    int t = threadIdx.x;
    int v = (t < P) ? part[t] : 0;
    s[t] = v; __syncthreads();
    for (int d = 1; d < 512; d <<= 1) {
        int x = (t >= d) ? s[t - d] : 0;
        __syncthreads();
        s[t] += x;
        __syncthreads();
    }
    if (t < P) part[t] = s[t] - v;
}

__global__ __launch_bounds__(256) void scan3_k(const int* part, int* off, int* cursor, int Nn, int Etot) {
    int i = blockIdx.x * 256 + threadIdx.x;
    if (i < Nn) {
        int o = off[i] + part[i >> 8];
        off[i] = o;
        cursor[i] = o;
    }
    if (i == 0) off[Nn] = Etot;
}

__global__ __launch_bounds__(256) void fill_k(
    const int* src, const int* dst, int* cursor, int* srcp, int* eidx, int Ecnt)
{
    int e = blockIdx.x * 256 + threadIdx.x;
    if (e < Ecnt) {
        int p = atomicAdd(&cursor[dst[e]], 1);
        srcp[p] = src[e];
        eidx[p] = e;
    }
}

// ---------------- permute ef rows into CSR order as bf16 ----------------
__global__ __launch_bounds__(256) void permute_k(
    const int* flag, const void* ef, const int* __restrict__ eidx,
    bf16* __restrict__ efp, int Ecnt)
{
    int i = blockIdx.x * 256 + threadIdx.x;
    if (i >= Ecnt) return;
    int e = eidx[i];
    unsigned short row[16];
    if (*flag) {
        const float* er = (const float*)ef + (size_t)e * FE_;
#pragma unroll
        for (int k = 0; k < FE_; k++) row[k] = f2us(er[k]);
    } else {
        const unsigned short* er = (const unsigned short*)ef + (size_t)e * FE_;
#pragma unroll
        for (int k = 0; k < FE_; k++) row[k] = er[k];
    }
    ushort4* o = (ushort4*)(efp + (size_t)i * FE_);
#pragma unroll
    for (int q = 0; q < 4; q++)
        o[q] = ushort4{row[4 * q], row[4 * q + 1], row[4 * q + 2], row[4 * q + 3]};
}

// ---------------- CSR message pass v3: streamed efp, 4-edge unroll ----------------
__global__ __launch_bounds__(256) void msg3_k(
    const bf16* __restrict__ efp, const int* __restrict__ srcp,
    const int* __restrict__ off, const bf16* __restrict__ h,
    const float* __restrict__ Wef, const float* __restrict__ bef,
    bf16* __restrict__ aggb, int Nn)
{
    const int tid = threadIdx.x;
    if (tid >= HN) return;
    const int n0 = blockIdx.x * NPB;
    float wcol[FE_];
#pragma unroll
    for (int k = 0; k < FE_; k++) wcol[k] = Wef[k * HN + tid];
    const float bj = bef[tid];

    for (int dd = 0; dd < NPB; dd++) {
        int d = n0 + dd;
        if (d >= Nn) break;
        int i0 = off[d], i1 = off[d + 1];
        float a = 0.f;
        int i = i0;
        for (; i + 4 <= i1; i += 4) {
            int s0 = srcp[i], s1 = srcp[i + 1], s2 = srcp[i + 2], s3 = srcp[i + 3];
            const short8v* fr = (const short8v*)(efp + (size_t)i * FE_);
            short8v fa0 = fr[0], fb0 = fr[1], fa1 = fr[2], fb1 = fr[3];
            short8v fa2 = fr[4], fb2 = fr[5], fa3 = fr[6], fb3 = fr[7];
            unsigned short h0 = *(const unsigned short*)&h[(size_t)s0 * HN + tid];
            unsigned short h1 = *(const unsigned short*)&h[(size_t)s1 * HN + tid];
            unsigned short h2 = *(const unsigned short*)&h[(size_t)s2 * HN + tid];
            unsigned short h3 = *(const unsigned short*)&h[(size_t)s3 * HN + tid];
            float g0 = bj, g1 = bj, g2 = bj, g3 = bj;
#pragma unroll
            for (int k = 0; k < 8; k++) {
                g0 = fmaf(us2f((unsigned short)fa0[k]), wcol[k], g0);
                g1 = fmaf(us2f((unsigned short)fa1[k]), wcol[k], g1);
                g2 = fmaf(us2f((unsigned short)fa2[k]), wcol[k], g2);
                g3 = fmaf(us2f((unsigned short)fa3[k]), wcol[k], g3);
            }
#pragma unroll
            for (int k = 0; k < 8; k++) {
                g0 = fmaf(us2f((unsigned short)fb0[k]), wcol[8 + k], g0);
                g1 = fmaf(us2f((unsigned short)fb1[k]), wcol[8 + k], g1);
                g2 = fmaf(us2f((unsigned short)fb2[k]), wcol[8 + k], g2);
                g3 = fmaf(us2f((unsigned short)fb3[k]), wcol[8 + k], g3);
            }
            a = fmaf(sigmf(g0), us2f(h0), a);
            a = fmaf(sigmf(g1), us2f(h1), a);
            a = fmaf(sigmf(g2), us2f(h2), a);
            a = fmaf(sigmf(g3), us2f(h3), a);
        }
        for (; i < i1; i++) {
            int s = srcp[i];
            const short8v* fr = (const short8v*)(efp + (size_t)i * FE_);
            short8v fa = fr[0], fb = fr[1];
            float g = bj;
#pragma unroll
            for (int k = 0; k < 8; k++) g = fmaf(us2f((unsigned short)fa[k]), wcol[k], g);
#pragma unroll
            for (int k = 0; k < 8; k++) g = fmaf(us2f((unsigned short)fb[k]), wcol[8 + k], g);
            a = fmaf(sigmf(g), b2f(h[(size_t)s * HN + tid]), a);
        }
        aggb[(size_t)d * HN + tid] = __float2bfloat16(a);
    }
}

// ---------------- generic MFMA GEMM (+optional fused score col 200) ----------------
__global__ __launch_bounds__(128) void gemmm_k(
    const int* flag, int xmode, const void* X, int K, int xstride, int KT,
    const short* __restrict__ WBp, const float* __restrict__ bp, int relu,
    bf16* __restrict__ out, int ostride, float* __restrict__ scoreOut, int Nn)
{
    __shared__ unsigned short Xs[32][232];
    const int tid = threadIdx.x;
    const int w = tid >> 6, lane = tid & 63;
    const int qd = lane >> 4, c0 = lane & 15;
    const int n0 = blockIdx.x * 32;
    const int xf32 = (xmode == 2) ? *flag : xmode;
    const int chunks = (KT * 32) >> 2;

    for (int i = tid; i < 32 * chunks; i += 128) {
        int row = i / chunks, c4 = (i - row * chunks) << 2;
        int grow = n0 + row;
        ushort4 v = ushort4{0, 0, 0, 0};
        if (grow < Nn && c4 < K) {
            if (xf32) {
                const float* xr = (const float*)X + (size_t)grow * xstride + c4;
                float4 fv = *(const float4*)xr;
                v = ushort4{f2us(fv.x), f2us(fv.y), f2us(fv.z), f2us(fv.w)};
            } else {
                v = *(const ushort4*)((const bf16*)X + (size_t)grow * xstride + c4);
            }
        }
        *(ushort4*)&Xs[row][c4] = v;
    }
    __syncthreads();

    const int ct0 = w * 7;
    const int ctn = w ? (CTN - 7) : 7;
    f32x4 acc[2][7];
#pragma unroll
    for (int mt = 0; mt < 2; mt++)
#pragma unroll
        for (int ctl = 0; ctl < 7; ctl++)
            acc[mt][ctl] = f32x4{0.f, 0.f, 0.f, 0.f};

    for (int kt = 0; kt < KT; kt++) {
        short8v a0 = *(const short8v*)&Xs[c0][kt * 32 + qd * 8];
        short8v a1 = *(const short8v*)&Xs[16 + c0][kt * 32 + qd * 8];
        const short* wp = WBp + ((size_t)kt * CTN + ct0) * 512 + lane * 8;
#pragma unroll
        for (int ctl = 0; ctl < 7; ctl++) {
            if (ctl < ctn) {
                short8v b = *(const short8v*)(wp + (size_t)ctl * 512);
                acc[0][ctl] = MFMA16(a0, b, acc[0][ctl]);
                acc[1][ctl] = MFMA16(a1, b, acc[1][ctl]);
            }
        }
    }

#pragma unroll
    for (int mt = 0; mt < 2; mt++)
#pragma unroll
        for (int ctl = 0; ctl < 7; ctl++) {
            if (ctl < ctn) {
#pragma unroll
                for (int r = 0; r < 4; r++) {
                    int row = n0 + mt * 16 + qd * 4 + r;
                    int col = (ct0 + ctl) * 16 + c0;
                    if (row < Nn) {
                        if (col < HN) {
                            float v = acc[mt][ctl][r] + bp[col];
                            if (relu) v = fmaxf(v, 0.f);
                            out[(size_t)row * ostride + col] = __float2bfloat16(v);
                        } else if (col == HN && scoreOut) {
                            scoreOut[row] = acc[mt][ctl][r] + bp[HN];
                        }
                    }
                }
            }
        }
}

// ---------------- fused MFMA tower-mix + GRU v3: 64 rows, 8 waves, no zbuf ----------------
// 39 col-tiles (z|r|q) dealt c = 8j+w, j<5. Phase0 m-GEMM writes m straight into the
// LDS m-slot; z is parked (bf16) in the m-slot after phase1 (m-slot is dead then).
__global__ __launch_bounds__(512) void gru3_k(
    const bf16* __restrict__ aggb, bf16* __restrict__ h,
    const short* __restrict__ WB, const float* __restrict__ bpack,
    const short* __restrict__ WBmix, const float* __restrict__ bpmix, int Nn)
{
    __shared__ unsigned short Xs[MB3][XSTR];   // [m-slot 0..223 | h-slot 224..447]
    const int tid = threadIdx.x;
    const int w = tid >> 6, lane = tid & 63;
    const int qd = lane >> 4, c0 = lane & 15;
    const int n0 = blockIdx.x * MB3;

    // stage agg -> m-slot, h -> h-slot (zero pads / OOB rows)
    for (int i = tid; i < MB3 * (XSTR / 4); i += 512) {
        int row = i / (XSTR / 4);
        int c4 = (i - row * (XSTR / 4)) * 4;
        int grow = n0 + row;
        ushort4 v = ushort4{0, 0, 0, 0};
        if (grow < Nn) {
            if (c4 < HN)
                v = *(const ushort4*)&aggb[(size_t)grow * HN + c4];
            else if (c4 >= 224 && c4 < 224 + HN)
                v = *(const ushort4*)&h[(size_t)grow * HN + (c4 - 224)];
        }
        *(ushort4*)&Xs[row][c4] = v;
    }
    __syncthreads();

    f32x4 acc[4][5];
    short8v a[4];

    // ---- phase 0: m = relu(agg @ W_eff + b_mix); tiles c = 8j+w < 13 (j<2) ----
#pragma unroll
    for (int mt = 0; mt < 4; mt++)
#pragma unroll
        for (int j = 0; j < 2; j++) acc[mt][j] = f32x4{0.f, 0.f, 0.f, 0.f};
    for (int kt = 0; kt < 7; kt++) {
#pragma unroll
        for (int mt = 0; mt < 4; mt++)
            a[mt] = *(const short8v*)&Xs[mt * 16 + c0][kt * 32 + qd * 8];
#pragma unroll
        for (int j = 0; j < 2; j++) {
            int c = 8 * j + w;
            if (c < 13) {
                short8v b = *(const short8v*)(WBmix + ((size_t)kt * CTN + c) * 512 + lane * 8);
#pragma unroll
                for (int mt = 0; mt < 4; mt++) acc[mt][j] = MFMA16(a[mt], b, acc[mt][j]);
            }
        }
    }
    __syncthreads();   // all phase-0 reads of m-slot done

    // write m (bf16) directly into m-slot; pads 200..223 stay 0 from staging
#pragma unroll
    for (int j = 0; j < 2; j++) {
        int c = 8 * j + w;
        if (c < 13) {
#pragma unroll
            for (int mt = 0; mt < 4; mt++)
#pragma unroll
                for (int r = 0; r < 4; r++) {
                    int row = mt * 16 + qd * 4 + r;
                    int col = c * 16 + c0;
                    if (col < HN)
                        Xs[row][col] = f2us(fmaxf(acc[mt][j][r] + bpmix[col], 0.f));
                }
        }
    }
    __syncthreads();

    // ---- phase 1: [z|r|q] = [m|h] @ [[Wz|Wr|Wh],[Uz|Ur|0]]; q tiles kt<7 only ----
    const short* wbase[5];
    int cdx[5], gdx[5];
#pragma unroll
    for (int j = 0; j < 5; j++) {
        int c = 8 * j + w;
        cdx[j] = c;
        int g = (c < 13) ? 0 : (c < 26) ? 1 : 2;
        gdx[j] = g;
        int ctl = c - g * 13;
        wbase[j] = WB + ((size_t)(g * KTN) * CTN + ctl) * 512 + lane * 8;
#pragma unroll
        for (int mt = 0; mt < 4; mt++) acc[mt][j] = f32x4{0.f, 0.f, 0.f, 0.f};
    }
    for (int kt = 0; kt < KTN; kt++) {
#pragma unroll
        for (int mt = 0; mt < 4; mt++)
            a[mt] = *(const short8v*)&Xs[mt * 16 + c0][kt * 32 + qd * 8];
#pragma unroll
        for (int j = 0; j < 5; j++) {
            if (cdx[j] < 39 && (gdx[j] < 2 || kt < 7)) {
                short8v b = *(const short8v*)(wbase[j] + (size_t)kt * CTN * 512);
#pragma unroll
                for (int mt = 0; mt < 4; mt++) acc[mt][j] = MFMA16(a[mt], b, acc[mt][j]);
            }
        }
    }
    __syncthreads();   // all phase-1 reads done

    // elementwise: z -> m-slot (bf16); r -> h-slot := bf16(r*h); q stays in regs
#pragma unroll
    for (int j = 0; j < 5; j++) {
        int c = cdx[j];
        if (c < 13) {
#pragma unroll
            for (int mt = 0; mt < 4; mt++)
#pragma unroll
                for (int r = 0; r < 4; r++) {
                    int row = mt * 16 + qd * 4 + r;
                    int col = c * 16 + c0;
                    if (col < HN)
                        Xs[row][col] = f2us(sigmf(acc[mt][j][r] + bpack[col]));
                }
        } else if (c < 26) {
            int ctl = c - 13;
#pragma unroll
            for (int mt = 0; mt < 4; mt++)
#pragma unroll
                for (int r = 0; r < 4; r++) {
                    int row = mt * 16 + qd * 4 + r;
                    int col = ctl * 16 + c0;
                    float rr = sigmf(acc[mt][j][r] + bpack[208 + col]);
                    float hv = us2f(Xs[row][224 + col]);
                    Xs[row][224 + col] = f2us(rr * hv);   // pads: hv=0 -> writes 0, safe
                }
        }
    }
    __syncthreads();   // z + r*h visible

    // ---- phase 2: q += (r*h) @ Uh (kt 7..13 of g=2 pack) ----
    for (int kt = 7; kt < KTN; kt++) {
#pragma unroll
        for (int mt = 0; mt < 4; mt++)
            a[mt] = *(const short8v*)&Xs[mt * 16 + c0][kt * 32 + qd * 8];
#pragma unroll
        for (int j = 0; j < 5; j++) {
            int c = cdx[j];
            if (c >= 26 && c < 39) {
                int ctl = c - 26;
                short8v b = *(const short8v*)(WB + ((size_t)(2 * KTN + kt) * CTN + ctl) * 512 + lane * 8);
#pragma unroll
                for (int mt = 0; mt < 4; mt++) acc[mt][j] = MFMA16(a[mt], b, acc[mt][j]);
            }
        }
    }

    // epilogue: h = h + z*(tanh(q + bh) - h), z from m-slot
#pragma unroll
    for (int j = 0; j < 5; j++) {
        int c = cdx[j];
        if (c >= 26 && c < 39) {
            int ctl = c - 26;
#pragma unroll
            for (int mt = 0; mt < 4; mt++)
#pragma unroll
                for (int r = 0; r < 4; r++) {
                    int row = mt * 16 + qd * 4 + r;
                    int col = ctl * 16 + c0;
                    int grow = n0 + row;
                    if (col < HN && grow < Nn) {
                        float ah = acc[mt][j][r] + bpack[416 + col];
                        ah = fminf(fmaxf(ah, -15.f), 15.f);
                        float e = __expf(2.f * ah);
                        float htl = (e - 1.f) / (e + 1.f);
                        float zv = us2f(Xs[row][col]);
                        size_t idx = (size_t)grow * HN + col;
                        float hv = b2f(h[idx]);
                        h[idx] = __float2bfloat16(fmaf(zv, htl - hv, hv));
                    }
                }
        }
    }
}

// ---------------- segment max ----------------
__global__ __launch_bounds__(256) void gmax_k(
    const float* __restrict__ score, const int* __restrict__ bv,
    unsigned* __restrict__ gmax_u, int Nn)
{
    __shared__ unsigned lm[GG];
    const int tid = threadIdx.x;
    for (int i = tid; i < GG; i += 256) lm[i] = 0u;
    __syncthreads();
    int n = blockIdx.x * 256 + tid;
    if (n < Nn) atomicMax(&lm[bv[n]], ordkey(score[n]));
    __syncthreads();
    for (int i = tid; i < GG; i += 256)
        if (lm[i]) atomicMax(&gmax_u[i], lm[i]);
}

// ---------------- exp + segment sum ----------------
__global__ __launch_bounds__(256) void exsum_k(
    const float* __restrict__ score, const int* __restrict__ bv,
    const unsigned* __restrict__ gmax_u, float* __restrict__ ex,
    float* __restrict__ gsum, int Nn)
{
    __shared__ float ls[GG];
    const int tid = threadIdx.x;
    for (int i = tid; i < GG; i += 256) ls[i] = 0.f;
    __syncthreads();
    int n = blockIdx.x * 256 + tid;
    if (n < Nn) {
        int g = bv[n];
        float e = __expf(score[n] - ordinv(gmax_u[g]));
        ex[n] = e;
        atomicAdd(&ls[g], e);
    }
    __syncthreads();
    for (int i = tid; i < GG; i += 256)
        if (ls[i] != 0.f) atomicAdd(&gsum[i], ls[i]);
}

// ---------------- weighted readout scatter ----------------
__global__ __launch_bounds__(256) void scatter_k(
    const bf16* __restrict__ feat, const float* __restrict__ ex,
    const float* __restrict__ gsum, const int* __restrict__ bv,
    float* __restrict__ gout, int Nn)
{
    const int tid = threadIdx.x;
    if (tid >= HN) return;
    int n0 = blockIdx.x * NRB;
    int lim = Nn - n0; if (lim > NRB) lim = NRB;
    float acc = 0.f;
    int cur = -1;
    float inv = 0.f;
    for (int i = 0; i < lim; i++) {
        int n = n0 + i;
        int g = bv[n];
        if (g != cur) {
            if (cur >= 0) atomicAdd(&gout[cur * HN + tid], acc);
            acc = 0.f;
            cur = g;
            inv = 1.0f / gsum[g];
        }
        acc = fmaf(ex[n] * inv, b2f(feat[(size_t)n * HN + tid]), acc);
    }
    if (cur >= 0) atomicAdd(&gout[cur * HN + tid], acc);
}

// ---------------- readout MLP ----------------
template <typename T, int OUTF32>
__device__ __forceinline__ void final_impl(
    float* r1s, const float* gout,
    const void* Wr1, const void* br1, const void* Wout, const void* bout,
    void* out, int g, int tid)
{
    if (tid < HN) {
        float v = LDR<T>::get(br1, tid);
        for (int k = 0; k < HN; k++) v = fmaf(gout[g * HN + k], LDR<T>::get(Wr1, (size_t)k * HN + tid), v);
        r1s[tid] = (v == v) ? fmaxf(v, 0.f) : v;
    }
    __syncthreads();
    if (tid < 64) {
        float a = 0.f;
        for (int k = tid; k < HN; k += 64) a = fmaf(r1s[k], LDR<T>::get(Wout, k), a);
        for (int off = 32; off; off >>= 1) a += __shfl_down(a, off, 64);
        if (tid == 0) {
            float res = a + LDR<T>::get(bout, 0);
            if (OUTF32) ((float*)out)[g] = res;
            else        ((bf16*)out)[g] = __float2bfloat16(res);
        }
    }
}

__global__ __launch_bounds__(256) void final_k(
    const int* flag, const float* gout,
    const void* Wr1, const void* br1, const void* Wout, const void* bout, void* out)
{
    __shared__ float r1s[HN];
    const int g = blockIdx.x, tid = threadIdx.x;
    if (*flag) final_impl<float, 1>(r1s, gout, Wr1, br1, Wout, bout, out, g, tid);
    else       final_impl<bf16,  0>(r1s, gout, Wr1, br1, Wout, bout, out, g, tid);
}

extern "C" void kernel_launch(void* const* d_in, const int* in_sizes, int n_in,
                              void* d_out, int out_size, void* d_ws, size_t ws_size,
                              hipStream_t stream)
{
    const void* nf      = d_in[0];
    const void* ef      = d_in[1];
    const int*  ei      = (const int*)d_in[2];
    const int*  bv      = (const int*)d_in[3];
    const void* W_in    = d_in[4];
    const void* b_in    = d_in[5];
    const void* W_edge  = d_in[6];
    const void* b_edge  = d_in[7];
    const void* W_tower = d_in[8];
    const void* W_mix   = d_in[9];
    const void* b_mix   = d_in[10];
    const void* Wz      = d_in[11];
    const void* Uz      = d_in[12];
    const void* bz      = d_in[13];
    const void* Wr      = d_in[14];
    const void* Ur      = d_in[15];
    const void* br      = d_in[16];
    const void* Wh      = d_in[17];
    const void* Uh      = d_in[18];
    const void* bh      = d_in[19];
    const void* W_score = d_in[20];
    const void* b_score = d_in[21];
    const void* W_feat  = d_in[22];
    const void* b_feat  = d_in[23];
    const void* W_r1    = d_in[24];
    const void* b_r1    = d_in[25];
    const void* W_out   = d_in[26];
    const void* b_out   = d_in[27];

    const int* src = ei;
    const int* dst = ei + EE;

    // ---- workspace layout (~115 MB) ----
    const size_t NH = (size_t)NN * HN;
    char* p = (char*)d_ws;
    auto take = [&](size_t bytes) { char* r = p; p += (bytes + 15) & ~(size_t)15; return r; };
    bf16*  h      = (bf16*)take(NH * 2);
    bf16*  aggb   = (bf16*)take(NH * 2);        // bf16 agg; feat reuses
    float* score  = (float*)take(NN * 4);
    float* ex     = (float*)take(NN * 4);
    unsigned* gmax_u = (unsigned*)take((GG + GG + GG * HN) * 4);
    float* gsum   = (float*)(gmax_u + GG);
    float* gout   = gsum + GG;
    short* WB     = (short*)take(WBSZ * 2);
    float* bpack  = (float*)take(3 * 208 * 4);
    short* WBmix  = (short*)take(7 * CTN * 512 * 2);
    float* bpmix  = (float*)take(208 * 4);
    short* WBfs   = (short*)take(7 * CTN * 512 * 2);
    float* bpfs   = (float*)take(208 * 4);
    short* WBin   = (short*)take(4 * CTN * 512 * 2);
    float* bpin   = (float*)take(208 * 4);
    float* Wef    = (float*)take(FE_ * HN * 4);
    float* bef    = (float*)take(HN * 4);
    int*   cnt    = (int*)take(NN * 4);
    int*   off    = (int*)take((NN + 1) * 4);
    int*   cursor = (int*)take(NN * 4);
    int*   part   = (int*)take(512 * 4);
    int*   srcp   = (int*)take(EE * 4);
    int*   eidx   = (int*)take(EE * 4);
    bf16*  efp    = (bf16*)take((size_t)EE * FE_ * 2);
    int*   flag   = (int*)take(16);

    const dim3 blk(256);
    const int zsmall_n4 = (GG + GG + GG * HN) / 4;

    probe_k<<<dim3(1), blk, 0, stream>>>(nf, W_in, flag);

    pack_all_k<<<dim3((PA_TOT + 255) / 256), blk, 0, stream>>>(
        flag, Wz, Uz, bz, Wr, Ur, br, Wh, Uh, bh,
        W_tower, W_mix, b_mix, W_feat, b_feat, W_score, b_score,
        W_in, b_in, W_edge, b_edge,
        WB, bpack, WBmix, bpmix, WBfs, bpfs, WBin, bpin, Wef, bef);

    // CSR build + ef permute (once per launch)
    zero_k<<<dim3((NN / 4 + 255) / 256), blk, 0, stream>>>((float4*)cnt, NN / 4);
    hist_k<<<dim3(EE / 256), blk, 0, stream>>>(dst, cnt, EE);
    const int SB = (NN + 255) / 256;
    scan1_k<<<dim3(SB), blk, 0, stream>>>(cnt, off, part, NN);
    scan2_k<<<dim3(1), dim3(512), 0, stream>>>(part, SB);
    scan3_k<<<dim3(SB), blk, 0, stream>>>(part, off, cursor, NN, EE);
    fill_k<<<dim3(EE / 256), blk, 0, stream>>>(src, dst, cursor, srcp, eidx, EE);
    permute_k<<<dim3(EE / 256), blk, 0, stream>>>(flag, ef, eidx, efp, EE);

    // h = relu(nf @ W_in + b_in)
    gemmm_k<<<dim3(NN / 32), dim3(128), 0, stream>>>(
        flag, 2, nf, FN_, FN_, 4, WBin, bpin, 1, h, HN, (float*)nullptr, NN);

    for (int s = 0; s < STEPS_; s++) {
        msg3_k<<<dim3((NN + NPB - 1) / NPB), blk, 0, stream>>>(
            efp, srcp, off, h, Wef, bef, aggb, NN);
        gru3_k<<<dim3((NN + MB3 - 1) / MB3), dim3(512), 0, stream>>>(
            aggb, h, WB, bpack, WBmix, bpmix, NN);
    }

    // readout: feat GEMM with fused score column
    zero_k<<<dim3((zsmall_n4 + 255) / 256), blk, 0, stream>>>((float4*)gmax_u, zsmall_n4);
    gemmm_k<<<dim3(NN / 32), dim3(128), 0, stream>>>(
        flag, 0, h, HN, HN, 7, WBfs, bpfs, 0, aggb, HN, score, NN);
    gmax_k<<<dim3((NN + 255) / 256), blk, 0, stream>>>(score, bv, gmax_u, NN);
    exsum_k<<<dim3((NN + 255) / 256), blk, 0, stream>>>(score, bv, gmax_u, ex, gsum, NN);
    scatter_k<<<dim3((NN + NRB - 1) / NRB), blk, 0, stream>>>(aggb, ex, gsum, bv, gout, NN);
    final_k<<<dim3(GG), blk, 0, stream>>>(flag, gout, W_r1, b_r1, W_out, b_out, d_out);
}